// Round 4
// baseline (130.058 us; speedup 1.0000x reference)
//
#include <hip/hip_runtime.h>
#include <stdint.h>

#define BSZ  4
#define NSEQ 2048
#define DM   128
#define NH   8
#define DK   16
#define LOG2E 1.4426950408889634f
// LOG2E / sqrt(128): folded into Wq/bq so scores exit QK^T in log2 domain
#define SCALE_QL 0.1275156338341935f
// mask weight: w = mask * 2^-18 (exact in bf16); folded into V' and the
// l-reduction A-operand. p = exp2(S) stays <= ~2^10, l ~ 1e-2 -> safe fp32.
#define W_SCALE 3.814697265625e-6f

typedef __bf16          bf16x8v __attribute__((ext_vector_type(8)));
typedef float           f32x4   __attribute__((ext_vector_type(4)));
typedef float           f32x16  __attribute__((ext_vector_type(16)));
typedef unsigned short  u16x8   __attribute__((ext_vector_type(8)));
typedef unsigned short  u16x4   __attribute__((ext_vector_type(4)));
typedef unsigned int    u32x2   __attribute__((ext_vector_type(2)));
typedef unsigned int    u32x4   __attribute__((ext_vector_type(4)));

__device__ __forceinline__ unsigned short f2bf(float f) {
    unsigned u = __float_as_uint(f);
    u = (u + 0x7fffu + ((u >> 16) & 1u)) >> 16;
    return (unsigned short)u;
}

__device__ __forceinline__ unsigned int pack2bf(float a, float b) {
#if __has_builtin(__builtin_amdgcn_cvt_pk_bf16_f32)
    typedef __bf16 bf16x2 __attribute__((ext_vector_type(2)));
    bf16x2 v = __builtin_amdgcn_cvt_pk_bf16_f32(a, b);
    return __builtin_bit_cast(unsigned int, v);
#else
    return (unsigned)f2bf(a) | ((unsigned)f2bf(b) << 16);
#endif
}

__device__ __forceinline__ float exp2_(float x) {
#if __has_builtin(__builtin_amdgcn_exp2f)
    return __builtin_amdgcn_exp2f(x);
#else
    return exp2f(x);
#endif
}

// load 8 consecutive f32, scale, convert -> u16x8 bf16 fragment
__device__ __forceinline__ u16x8 cvt8(const float* p, float sc) {
    const f32x4 a = *reinterpret_cast<const f32x4*>(p);
    const f32x4 b = *reinterpret_cast<const f32x4*>(p + 4);
    u32x4 u = {pack2bf(a[0] * sc, a[1] * sc), pack2bf(a[2] * sc, a[3] * sc),
               pack2bf(b[0] * sc, b[1] * sc), pack2bf(b[2] * sc, b[3] * sc)};
    return __builtin_bit_cast(u16x8, u);
}

__device__ __forceinline__ f32x4 mfma16(u16x8 a, u16x8 b, f32x4 c) {
    return __builtin_amdgcn_mfma_f32_16x16x32_bf16(
        __builtin_bit_cast(bf16x8v, a), __builtin_bit_cast(bf16x8v, b), c, 0, 0, 0);
}
__device__ __forceinline__ f32x16 mfma32(u16x8 a, u16x8 b, f32x16 c) {
    return __builtin_amdgcn_mfma_f32_32x32x16_bf16(
        __builtin_bit_cast(bf16x8v, a), __builtin_bit_cast(bf16x8v, b), c, 0, 0, 0);
}

// ---------------------------------------------------------------------------
// k_qkv: C^T-form projection, x-tile staged in LDS (coalesced f32x4 loads).
// grid = b(4) x n-tile32(64), 768 threads = 12 waves = mat(3) x nsub(2) x th(2).
// V is scaled by w = mask*2^-18 at generation (V' = V*w).
// Side-job: WfcB = bf16(Wfc); wb = bf16(mask*2^-18).
// Q,K -> [B][H][N][16] bf16 ; V' -> transposed [B][H][16][N] bf16.
// ---------------------------------------------------------------------------
__global__ __launch_bounds__(768) void k_qkv(
    const float* __restrict__ x,
    const float* __restrict__ Wq, const float* __restrict__ bq,
    const float* __restrict__ Wk, const float* __restrict__ bk,
    const float* __restrict__ Wv, const float* __restrict__ bv,
    const float* __restrict__ Wfc, const float* __restrict__ mask,
    unsigned short* __restrict__ Q, unsigned short* __restrict__ Kb,
    unsigned short* __restrict__ Vt,
    unsigned short* __restrict__ WfcB, unsigned short* __restrict__ wb)
{
    __shared__ __align__(16) float xs[DM * 36];   // 32 n + 4 pad
    const int tid = threadIdx.x;

    // side job (consumed by LATER kernels only)
    const int gt = blockIdx.x * 768 + tid;
    if (gt < DM * DM) {
        WfcB[gt] = f2bf(Wfc[gt]);
    } else if (gt < DM * DM + BSZ * NSEQ) {
        const int i = gt - DM * DM;
        wb[i] = f2bf(mask[i] * W_SCALE);
    }

    const int b  = blockIdx.x >> 6;
    const int n0 = (blockIdx.x & 63) << 5;

    // stage x[b][0..128][n0..n0+32] -> xs[d*36 + j], fully coalesced
#pragma unroll
    for (int i = tid; i < 1024; i += 768) {
        const int d = i >> 3, c4 = (i & 7) << 2;
        *reinterpret_cast<f32x4*>(&xs[d * 36 + c4]) =
            *reinterpret_cast<const f32x4*>(x + (size_t)(b * DM + d) * NSEQ + n0 + c4);
    }
    __syncthreads();

    const int lane = tid & 63;
    const int wv   = tid >> 6;          // 0..11
    const int mat  = wv >> 2;           // 0..2
    const int nt   = (wv >> 1) & 1;     // n subtile
    const int th   = wv & 1;            // t half
    const int c    = lane & 15;
    const int quad = lane >> 4;
    const int col  = n0 + nt * 16 + c;

    // B-frag from LDS: B[k=d][n=c]
    u16x8 xf[4];
#pragma unroll
    for (int kk = 0; kk < 4; ++kk) {
        float f[8];
#pragma unroll
        for (int j = 0; j < 8; ++j)
            f[j] = xs[(kk * 32 + quad * 8 + j) * 36 + nt * 16 + c];
        u32x4 u = {pack2bf(f[0], f[1]), pack2bf(f[2], f[3]),
                   pack2bf(f[4], f[5]), pack2bf(f[6], f[7])};
        xf[kk] = __builtin_bit_cast(u16x8, u);
    }

    const float* W    = (mat == 0) ? Wq : (mat == 1) ? Wk : Wv;
    const float* bias = (mat == 0) ? bq : (mat == 1) ? bk : bv;
    const float  sc   = (mat == 0) ? SCALE_QL : 1.0f;
    // V' scale: w = mask * 2^-18 for this column
    const float  vw   = (mat == 2) ? mask[b * NSEQ + col] * W_SCALE : 0.f;

#pragma unroll
    for (int tt = 0; tt < 4; ++tt) {
        const int t = th * 4 + tt;
        f32x4 acc = {0.f, 0.f, 0.f, 0.f};
#pragma unroll
        for (int kk = 0; kk < 4; ++kk)
            acc = mfma16(cvt8(W + (t * 16 + c) * DM + kk * 32 + quad * 8, sc),
                         xf[kk], acc);
        if (mat == 2) {
#pragma unroll
            for (int r = 0; r < 4; ++r)
                Vt[((b * NH + t) * DK + quad * 4 + r) * NSEQ + col] =
                    f2bf((acc[r] + bias[t * 16 + quad * 4 + r]) * vw);
        } else {
            u16x4 pk;
#pragma unroll
            for (int r = 0; r < 4; ++r)
                pk[r] = f2bf(acc[r] + bias[t * 16 + quad * 4 + r] * sc);
            *reinterpret_cast<u16x4*>(
                (mat == 0 ? Q : Kb) + ((size_t)(b * NH + t) * NSEQ + col) * DK +
                quad * 4) = pk;
        }
    }
}

// ---------------------------------------------------------------------------
// k_attn: fixed-scale flash attention, mask fully pre-folded (C-operand = 0,
// no mask loads in the loop). Block = 32-query tile, 4 waves = 4 kv quarters,
// 64 kv/iter, single 17 KB P buffer (per-wave in-order DS: RAW write->read
// within iter, WAR read->next-iter-write both safe).
// REGISTER-PRESSURE version (round-3 finding: occupancy pinned at 4 blocks/CU
// by ~115 UNIFIED VGPRs — arch count 60 excludes acc side; LDS was never the
// limiter). Changes: (a) S0/S1 processed SEPARATELY (one f32x16 live at a
// time, not two), (b) no cross-stage held P/V/w reads (pipelining measured
// neutral in round 1; it held +24 regs), (c) V loads at iter top (stage
// covers L2 latency), w loads late (L1-hot). Estimated peak ~75-80 regs ->
// __launch_bounds__(256, 6) (budget 85) for 6 blocks/CU. Spill tripwire:
// WRITE_SIZE ballooning (round-2 lesson) -> fall back to min-waves 5.
// XCD-chunked bid swizzle (round-3: FETCH 17.5 -> 3.1 MB, keep).
// l via MFMA with A = wb (mask weights).
// ---------------------------------------------------------------------------
__global__ __launch_bounds__(256, 6) void k_attn(
    const unsigned short* __restrict__ Q,
    const unsigned short* __restrict__ Kb,
    const unsigned short* __restrict__ Vt,
    const unsigned short* __restrict__ wb,
    unsigned short* __restrict__ AO)
{
    __shared__ __align__(16) char smem[17408];
    const int tid  = threadIdx.x;
    const int lane = tid & 63;
    const int w    = tid >> 6;      // kv quarter
    const int q32  = lane & 31;
    const int c    = lane & 15;
    const int quad = lane >> 4;
    const int hi   = lane >> 5;

    // XCD-chunked swizzle: hw round-robins bid%8 across XCDs; give each XCD
    // a contiguous 256-block logical chunk (= 4 complete (b,h) groups).
    const int bid = ((int)blockIdx.x & 7) * 256 + ((int)blockIdx.x >> 3);
    const int b  = bid >> 9;
    const int h  = (bid >> 6) & 7;
    const int n0 = (bid & 63) << 5;
    const int bh = b * NH + h;

    // Q B-frag (prescaled to log2 domain): B[k=8*hi+j][n=q32]
    const u16x8 uq = *reinterpret_cast<const u16x8*>(
        Q + ((size_t)bh * NSEQ + n0 + q32) * DK + 8 * hi);

    const unsigned short* Kp = Kb + (size_t)bh * NSEQ * DK + 8 * hi;
    const unsigned short* Vp = Vt + ((size_t)bh * DK + c) * NSEQ + 8 * quad;
    const unsigned short* wp = wb + b * NSEQ + 8 * quad;   // A-layout k idx

    // per-wave P staging: 32 rows (q) x 136 B (64 kv bf16 + 8B pad)
    char* pb = smem + w * 4352;
    char* wrow = pb + q32 * 136 + 8 * hi;
    const char* rrow0 = pb + c * 136 + 16 * quad;
    const char* rrow1 = pb + (c + 16) * 136 + 16 * quad;

    f32x4 o0 = {0.f, 0.f, 0.f, 0.f}, o1 = {0.f, 0.f, 0.f, 0.f};
    f32x4 l0 = {0.f, 0.f, 0.f, 0.f}, l1 = {0.f, 0.f, 0.f, 0.f};
    const f32x16 z16 = {};
    const int kvb = w * (NSEQ / 4);

    // prefetch iteration 0's K fragments
    u16x8 nk0 = *reinterpret_cast<const u16x8*>(Kp + (size_t)(kvb + q32) * DK);
    u16x8 nk1 = *reinterpret_cast<const u16x8*>(Kp + (size_t)(kvb + 32 + q32) * DK);

#pragma unroll 1
    for (int it = 0; it < 8; ++it) {
        const int kv0 = kvb + it * 64;

        // V loads at iter top: L2-resident, latency covered by the stage
        const u16x8 uv0 = *reinterpret_cast<const u16x8*>(Vp + kv0);
        const u16x8 uv1 = *reinterpret_cast<const u16x8*>(Vp + kv0 + 32);

        // --- S0 half: mfma -> exp2 -> pack -> write (one f32x16 live) ---
        {
            __builtin_amdgcn_s_setprio(1);
            f32x16 S0 = mfma32(nk0, uq, z16);   // S^T[kv][q] (log2 domain)
            __builtin_amdgcn_s_setprio(0);
            if (it < 7)                          // nk0 consumed -> refill
                nk0 = *reinterpret_cast<const u16x8*>(
                    Kp + (size_t)(kv0 + 64 + q32) * DK);
#pragma unroll
            for (int i = 0; i < 16; ++i) S0[i] = exp2_(S0[i]);
#pragma unroll
            for (int g = 0; g < 4; ++g) {
                u32x2 d = {pack2bf(S0[4 * g], S0[4 * g + 1]),
                           pack2bf(S0[4 * g + 2], S0[4 * g + 3])};
                *reinterpret_cast<u32x2*>(wrow + 16 * g) = d;
            }
        }

        // --- S1 half ---
        {
            __builtin_amdgcn_s_setprio(1);
            f32x16 S1 = mfma32(nk1, uq, z16);
            __builtin_amdgcn_s_setprio(0);
            if (it < 7)
                nk1 = *reinterpret_cast<const u16x8*>(
                    Kp + (size_t)(kv0 + 96 + q32) * DK);
#pragma unroll
            for (int i = 0; i < 16; ++i) S1[i] = exp2_(S1[i]);
#pragma unroll
            for (int g = 0; g < 4; ++g) {
                u32x2 d = {pack2bf(S1[4 * g], S1[4 * g + 1]),
                           pack2bf(S1[4 * g + 2], S1[4 * g + 3])};
                *reinterpret_cast<u32x2*>(wrow + 64 + 16 * g) = d;
            }
        }

        // --- P reads (in-order DS waits on the writes above) ---
        const u16x8 up0a = *reinterpret_cast<const u16x8*>(rrow0);
        const u16x8 up1a = *reinterpret_cast<const u16x8*>(rrow1);
        const u16x8 up0b = *reinterpret_cast<const u16x8*>(rrow0 + 64);
        const u16x8 up1b = *reinterpret_cast<const u16x8*>(rrow1 + 64);
        // w loads late (wb is 4 KB/batch, L1-hot)
        const u16x8 uw0 = *reinterpret_cast<const u16x8*>(wp + kv0);
        const u16x8 uw1 = *reinterpret_cast<const u16x8*>(wp + kv0 + 32);

        // --- PV + l: unnormalized; w folded into V' and uw ---
        __builtin_amdgcn_s_setprio(1);
        o0 = mfma16(uv0, up0a, o0);   // O^T[dk][q=c]
        o1 = mfma16(uv0, up1a, o1);   // q = 16+c
        l0 = mfma16(uw0, up0a, l0);   // all rows = sum_kv w*p (q=c)
        l1 = mfma16(uw0, up1a, l1);   // q = 16+c
        o0 = mfma16(uv1, up0b, o0);
        o1 = mfma16(uv1, up1b, o1);
        l0 = mfma16(uw1, up0b, l0);
        l1 = mfma16(uw1, up1b, l1);
        __builtin_amdgcn_s_setprio(0);
    }

    // ---- plain-sum 4-way merge (reuse P-staging LDS) ----
    __syncthreads();                       // all P reads done
    float* Lsm = reinterpret_cast<float*>(smem);          // [w][q] l partials
    float* Osm = reinterpret_cast<float*>(smem + 512);    // [w][q*20 + dk]
    Lsm[w * 32 + c]      = l0[0];          // all quads hold same value
    Lsm[w * 32 + 16 + c] = l1[0];
    *reinterpret_cast<f32x4*>(Osm + w * 640 + c * 20 + 4 * quad)        = o0;
    *reinterpret_cast<f32x4*>(Osm + w * 640 + (c + 16) * 20 + 4 * quad) = o1;
    __syncthreads();

    const int q   = tid >> 3;              // 0..31
    const int dk2 = (tid & 7) * 2;         // 0,2,..,14
    const float l = Lsm[q] + Lsm[32 + q] + Lsm[64 + q] + Lsm[96 + q];
    const float* Oq = Osm + q * 20 + dk2;
    const float v0 = Oq[0] + Oq[640] + Oq[1280] + Oq[1920];
    const float v1 = Oq[1] + Oq[641] + Oq[1281] + Oq[1921];
    const float inv = 1.0f / l;
    *reinterpret_cast<unsigned int*>(
        AO + ((size_t)(b * NSEQ) + n0 + q) * DM + h * DK + dk2) =
        pack2bf(v0 * inv, v1 * inv);
}

// ---------------------------------------------------------------------------
// k_fc: C^T-form FC, output directly in (B, D, N).
// grid = b(4) x n-tile(128) x t-half(2), 4 waves, wave = one d'-tile.
// ---------------------------------------------------------------------------
__global__ __launch_bounds__(256) void k_fc(
    const unsigned short* __restrict__ AO,
    const unsigned short* __restrict__ WfcB, const float* __restrict__ bfc,
    float* __restrict__ out)
{
    const int lane = threadIdx.x & 63;
    const int w    = threadIdx.x >> 6;
    const int c    = lane & 15;
    const int quad = lane >> 4;
    const int b    = blockIdx.x >> 8;
    const int n0   = ((blockIdx.x >> 1) & 127) << 4;
    const int t    = (blockIdx.x & 1) * 4 + w;

    u16x8 af[4];
#pragma unroll
    for (int kk = 0; kk < 4; ++kk)
        af[kk] = *reinterpret_cast<const u16x8*>(
            AO + ((size_t)(b * NSEQ) + n0 + c) * DM + kk * 32 + quad * 8);

    f32x4 acc = {0.f, 0.f, 0.f, 0.f};
#pragma unroll
    for (int kk = 0; kk < 4; ++kk)
        acc = mfma16(*reinterpret_cast<const u16x8*>(
                         WfcB + (t * 16 + c) * DM + kk * 32 + quad * 8),
                     af[kk], acc);
#pragma unroll
    for (int r = 0; r < 4; ++r)
        out[(size_t)(b * DM + t * 16 + quad * 4 + r) * NSEQ + n0 + c] =
            acc[r] + bfc[t * 16 + quad * 4 + r];
}

// ---------------------------------------------------------------------------
extern "C" void kernel_launch(void* const* d_in, const int* in_sizes, int n_in,
                              void* d_out, int out_size, void* d_ws, size_t ws_size,
                              hipStream_t stream)
{
    const float* x    = (const float*)d_in[0];
    const float* mask = (const float*)d_in[1];
    const float* Wq   = (const float*)d_in[2];
    const float* bq   = (const float*)d_in[3];
    const float* Wk   = (const float*)d_in[4];
    const float* bk   = (const float*)d_in[5];
    const float* Wv   = (const float*)d_in[6];
    const float* bv   = (const float*)d_in[7];
    const float* Wfc  = (const float*)d_in[8];
    const float* bfc  = (const float*)d_in[9];
    float* out = (float*)d_out;

    const size_t QKV_ELEMS = (size_t)BSZ * NH * NSEQ * DK;  // 1,048,576
    unsigned short* Q    = (unsigned short*)d_ws;
    unsigned short* Kb   = Q + QKV_ELEMS;
    unsigned short* Vt   = Kb + QKV_ELEMS;
    unsigned short* AO   = Vt + QKV_ELEMS;
    unsigned short* WfcB = AO + QKV_ELEMS;
    unsigned short* wb   = WfcB + DM * DM;

    k_qkv<<<256, 768, 0, stream>>>(x, Wq, bq, Wk, bk, Wv, bv, Wfc, mask,
                                   Q, Kb, Vt, WfcB, wb);
    k_attn<<<2048, 256, 0, stream>>>(Q, Kb, Vt, wb, AO);
    k_fc<<<1024, 256, 0, stream>>>(AO, WfcB, bfc, out);
}

// Round 6
// 122.379 us; speedup vs baseline: 1.0627x; 1.0627x over previous
//
#include <hip/hip_runtime.h>
#include <stdint.h>

#define BSZ  4
#define NSEQ 2048
#define DM   128
#define NH   8
#define DK   16
#define LOG2E 1.4426950408889634f
// LOG2E / sqrt(128): folded into Wq/bq so scores exit QK^T in log2 domain
#define SCALE_QL 0.1275156338341935f
// mask weight: w = mask * 2^-18 (exact in bf16); folded into V' and the
// l-row of the PV A-tile. p = exp2(S) stays <= ~2^10, l ~ 1e-2 -> safe fp32.
#define W_SCALE 3.814697265625e-6f

typedef __bf16          bf16x8v __attribute__((ext_vector_type(8)));
typedef float           f32x4   __attribute__((ext_vector_type(4)));
typedef float           f32x16  __attribute__((ext_vector_type(16)));
typedef unsigned short  u16x8   __attribute__((ext_vector_type(8)));
typedef unsigned short  u16x4   __attribute__((ext_vector_type(4)));
typedef unsigned int    u32x2   __attribute__((ext_vector_type(2)));
typedef unsigned int    u32x4   __attribute__((ext_vector_type(4)));

__device__ __forceinline__ unsigned short f2bf(float f) {
    unsigned u = __float_as_uint(f);
    u = (u + 0x7fffu + ((u >> 16) & 1u)) >> 16;
    return (unsigned short)u;
}

__device__ __forceinline__ unsigned int pack2bf(float a, float b) {
#if __has_builtin(__builtin_amdgcn_cvt_pk_bf16_f32)
    typedef __bf16 bf16x2 __attribute__((ext_vector_type(2)));
    bf16x2 v = __builtin_amdgcn_cvt_pk_bf16_f32(a, b);
    return __builtin_bit_cast(unsigned int, v);
#else
    return (unsigned)f2bf(a) | ((unsigned)f2bf(b) << 16);
#endif
}

__device__ __forceinline__ float exp2_(float x) {
#if __has_builtin(__builtin_amdgcn_exp2f)
    return __builtin_amdgcn_exp2f(x);
#else
    return exp2f(x);
#endif
}

// load 8 consecutive f32, scale, convert -> u16x8 bf16 fragment
__device__ __forceinline__ u16x8 cvt8(const float* p, float sc) {
    const f32x4 a = *reinterpret_cast<const f32x4*>(p);
    const f32x4 b = *reinterpret_cast<const f32x4*>(p + 4);
    u32x4 u = {pack2bf(a[0] * sc, a[1] * sc), pack2bf(a[2] * sc, a[3] * sc),
               pack2bf(b[0] * sc, b[1] * sc), pack2bf(b[2] * sc, b[3] * sc)};
    return __builtin_bit_cast(u16x8, u);
}

__device__ __forceinline__ f32x4 mfma16(u16x8 a, u16x8 b, f32x4 c) {
    return __builtin_amdgcn_mfma_f32_16x16x32_bf16(
        __builtin_bit_cast(bf16x8v, a), __builtin_bit_cast(bf16x8v, b), c, 0, 0, 0);
}
__device__ __forceinline__ f32x16 mfma32(u16x8 a, u16x8 b, f32x16 c) {
    return __builtin_amdgcn_mfma_f32_32x32x16_bf16(
        __builtin_bit_cast(bf16x8v, a), __builtin_bit_cast(bf16x8v, b), c, 0, 0, 0);
}

// Cross-half word exchange with UNAMBIGUOUS semantics (round-5 lesson:
// permlane32_swap's operand/return convention was assumed, not known, and
// produced a P<->V mispairing). ds_bpermute is a pure pull:
// out[lane] = src[bpi>>2], full wave64 (this is what __shfl compiles to).
// Pre-select halves the shuffle count: each lane SENDS the word its partner
// (lane^32) needs.  lo = this lane's low-kv word, hi_ = its high-kv word.
//   wA = fragment word for k-slots j=0,1  (hi=0: own lo ; hi=1: partner hi_)
//   wB = fragment word for k-slots j=4,5  (hi=0: partner lo ; hi=1: own hi_)
__device__ __forceinline__ void xpair(unsigned lo, unsigned hi_, int bpi, int isHi,
                                      unsigned& wA, unsigned& wB) {
    const unsigned send = isHi ? lo : hi_;
    const unsigned recv =
        (unsigned)__builtin_amdgcn_ds_bpermute(bpi, (int)send);
    wA = isHi ? recv : lo;
    wB = isHi ? hi_ : recv;
}

// ---------------------------------------------------------------------------
// k_qkv: C^T-form projection, x-tile staged in LDS (coalesced f32x4 loads).
// grid = b(4) x n-tile32(64), 768 threads = 12 waves = mat(3) x nsub(2) x th(2).
// Q,K -> [B][H][N][16] bf16.
// V is emitted directly as the PV A-tile VW2[bh][g=kv/16][lane][8]:
//   lane = row + 32*khalf (khalf = bit3 of kv), row 0-15 = V'[dk] (V scaled
//   by w=mask*2^-18), row 16 = w (so PV-MFMA computes l in C row 16),
//   rows 17-31 = garbage (their C rows are never read).
// Side-job: WfcB = bf16(Wfc); w-weave into VW2 row 16.
// ---------------------------------------------------------------------------
__global__ __launch_bounds__(768) void k_qkv(
    const float* __restrict__ x,
    const float* __restrict__ Wq, const float* __restrict__ bq,
    const float* __restrict__ Wk, const float* __restrict__ bk,
    const float* __restrict__ Wv, const float* __restrict__ bv,
    const float* __restrict__ Wfc, const float* __restrict__ mask,
    unsigned short* __restrict__ Q, unsigned short* __restrict__ Kb,
    unsigned short* __restrict__ VW2, unsigned short* __restrict__ WfcB)
{
    __shared__ __align__(16) float xs[DM * 36];   // 32 n + 4 pad
    const int tid = threadIdx.x;

    // side job (consumed by LATER kernels only)
    const int gt = blockIdx.x * 768 + tid;
    if (gt < DM * DM) {
        WfcB[gt] = f2bf(Wfc[gt]);
    } else if (gt < DM * DM + BSZ * NSEQ) {
        const int i  = gt - DM * DM;          // i = b*NSEQ + kv
        const int kv = i & (NSEQ - 1);
        const int bb = i >> 11;
        const unsigned short w16 = f2bf(mask[i] * W_SCALE);
        unsigned short* dst = VW2 +
            (((size_t)(bb * NH) * 128 + (kv >> 4)) << 9) +
            (16 + ((kv >> 3) & 1) * 32) * 8 + (kv & 7);
#pragma unroll
        for (int hh = 0; hh < NH; ++hh)
            dst[(size_t)hh * 128 * 512] = w16;
    }

    const int b  = blockIdx.x >> 6;
    const int n0 = (blockIdx.x & 63) << 5;

    // stage x[b][0..128][n0..n0+32] -> xs[d*36 + j], fully coalesced
#pragma unroll
    for (int i = tid; i < 1024; i += 768) {
        const int d = i >> 3, c4 = (i & 7) << 2;
        *reinterpret_cast<f32x4*>(&xs[d * 36 + c4]) =
            *reinterpret_cast<const f32x4*>(x + (size_t)(b * DM + d) * NSEQ + n0 + c4);
    }
    __syncthreads();

    const int lane = tid & 63;
    const int wv   = tid >> 6;          // 0..11
    const int mat  = wv >> 2;           // 0..2
    const int nt   = (wv >> 1) & 1;     // n subtile
    const int th   = wv & 1;            // t half
    const int c    = lane & 15;
    const int quad = lane >> 4;
    const int col  = n0 + nt * 16 + c;

    // B-frag from LDS: B[k=d][n=c]
    u16x8 xf[4];
#pragma unroll
    for (int kk = 0; kk < 4; ++kk) {
        float f[8];
#pragma unroll
        for (int j = 0; j < 8; ++j)
            f[j] = xs[(kk * 32 + quad * 8 + j) * 36 + nt * 16 + c];
        u32x4 u = {pack2bf(f[0], f[1]), pack2bf(f[2], f[3]),
                   pack2bf(f[4], f[5]), pack2bf(f[6], f[7])};
        xf[kk] = __builtin_bit_cast(u16x8, u);
    }

    const float* W    = (mat == 0) ? Wq : (mat == 1) ? Wk : Wv;
    const float* bias = (mat == 0) ? bq : (mat == 1) ? bk : bv;
    const float  sc   = (mat == 0) ? SCALE_QL : 1.0f;
    // V' scale: w = mask * 2^-18 for this column
    const float  vwsc = (mat == 2) ? mask[b * NSEQ + col] * W_SCALE : 0.f;
    const int    g    = col >> 4;
    const int    roff = ((col >> 3) & 1) * 32;
    const int    j7   = col & 7;

#pragma unroll
    for (int tt = 0; tt < 4; ++tt) {
        const int t = th * 4 + tt;
        f32x4 acc = {0.f, 0.f, 0.f, 0.f};
#pragma unroll
        for (int kk = 0; kk < 4; ++kk)
            acc = mfma16(cvt8(W + (t * 16 + c) * DM + kk * 32 + quad * 8, sc),
                         xf[kk], acc);
        if (mat == 2) {
            unsigned short* vwp = VW2 +
                (((size_t)((b * NH + t) * 128 + g)) << 9) + j7;
#pragma unroll
            for (int r = 0; r < 4; ++r)
                vwp[(quad * 4 + r + roff) * 8] =
                    f2bf((acc[r] + bias[t * 16 + quad * 4 + r]) * vwsc);
        } else {
            u16x4 pk;
#pragma unroll
            for (int r = 0; r < 4; ++r)
                pk[r] = f2bf(acc[r] + bias[t * 16 + quad * 4 + r] * sc);
            *reinterpret_cast<u16x4*>(
                (mat == 0 ? Q : Kb) + ((size_t)(b * NH + t) * NSEQ + col) * DK +
                quad * 4) = pk;
        }
    }
}

// ---------------------------------------------------------------------------
// k_attn: fixed-scale flash attention, ZERO LDS data staging in the main
// loop (round-4 finding: time invariant to occupancy; the LDS transpose
// round-trip serialized the dominant VALU/trans pipe at 44% duty).
// S = mfma32(K, Q) leaves, on lane (q=l&31, hi=l>>5), p[kvl] for
// kvl=(reg&3)+8*(reg>>2)+4*hi (HW-validated by the rounds 0-4 LDS path).
// The PV B-frag (B[k=8*hi+j][n=q]) is built IN REGISTERS: cvt_pk pairs,
// then one ds_bpermute(lane^32) per word-pair via xpair (pre-select: each
// lane sends what its partner needs). PV is mfma32 with A = VW2 tile:
// rows 0-15 = V', row 16 = w -> l falls out of the same MFMA (C row 16,
// reg 8 on hi=0 lanes); rows 17-31 garbage (C rows never read).
// No wb/uw loads, no P staging; LDS (10.8 KB) only for the epilogue merge.
// XCD-chunked bid swizzle (round-3: FETCH 17.5 -> 3.1 MB, keep).
// __launch_bounds__(256,4): proven no-spill regime (rounds 2/4 lessons);
// occupancy is NOT the lever for this kernel.
// ---------------------------------------------------------------------------
__global__ __launch_bounds__(256, 4) void k_attn(
    const unsigned short* __restrict__ Q,
    const unsigned short* __restrict__ Kb,
    const unsigned short* __restrict__ VW2,
    unsigned short* __restrict__ AO)
{
    __shared__ __align__(16) float smem[128 + 4 * 32 * 20];  // Lsm + Osm
    const int tid  = threadIdx.x;
    const int lane = tid & 63;
    const int w    = tid >> 6;      // kv quarter
    const int q32  = lane & 31;
    const int hi   = lane >> 5;
    const int bpi  = (lane ^ 32) << 2;   // bpermute partner index (bytes)

    // XCD-chunked swizzle: hw round-robins bid%8 across XCDs; give each XCD
    // a contiguous 256-block logical chunk (= 4 complete (b,h) groups).
    const int bid = ((int)blockIdx.x & 7) * 256 + ((int)blockIdx.x >> 3);
    const int b  = bid >> 9;
    const int h  = (bid >> 6) & 7;
    const int n0 = (bid & 63) << 5;
    const int bh = b * NH + h;

    // Q B-frag (prescaled to log2 domain): B[k=8*hi+j][n=q32]
    const u16x8 uq = *reinterpret_cast<const u16x8*>(
        Q + ((size_t)bh * NSEQ + n0 + q32) * DK + 8 * hi);

    const unsigned short* Kp = Kb + (size_t)bh * NSEQ * DK + 8 * hi;
    // PV A-tile: lane-linear, 16 B/lane fully coalesced
    const unsigned short* Ap = VW2 + (((size_t)bh * 128) << 9) + lane * 8;

    f32x16 acc = {};                  // O^T rows 0-15, l at row 16
    const f32x16 z16 = {};
    const int kvb = w * (NSEQ / 4);

    // prefetch iteration 0's K fragments
    u16x8 nk0 = *reinterpret_cast<const u16x8*>(Kp + (size_t)(kvb + q32) * DK);
    u16x8 nk1 = *reinterpret_cast<const u16x8*>(Kp + (size_t)(kvb + 32 + q32) * DK);

#pragma unroll 1
    for (int it = 0; it < 8; ++it) {
        const int kv0 = kvb + it * 64;
        const int g0  = kv0 >> 4;
        // PV A-frags for this iter's 4 K=16 tiles (L2-resident, issued early)
        const u16x8 va0 = *reinterpret_cast<const u16x8*>(Ap + ((size_t)(g0    ) << 9));
        const u16x8 va1 = *reinterpret_cast<const u16x8*>(Ap + ((size_t)(g0 + 1) << 9));
        const u16x8 va2 = *reinterpret_cast<const u16x8*>(Ap + ((size_t)(g0 + 2) << 9));
        const u16x8 va3 = *reinterpret_cast<const u16x8*>(Ap + ((size_t)(g0 + 3) << 9));

        // --- S0: kv [kv0, kv0+32) -> bf1 (group g0), bf2 (group g0+1) ---
        u16x8 bf1, bf2;
        {
            __builtin_amdgcn_s_setprio(1);
            f32x16 S = mfma32(nk0, uq, z16);   // S^T[kv][q] (log2 domain)
            __builtin_amdgcn_s_setprio(0);
            if (it < 7)
                nk0 = *reinterpret_cast<const u16x8*>(
                    Kp + (size_t)(kv0 + 64 + q32) * DK);
#pragma unroll
            for (int i = 0; i < 16; ++i) S[i] = exp2_(S[i]);
            // packed words; own kv = (pairs) 0,1|2,3 (+4*hi) etc.
            const unsigned a0 = pack2bf(S[0],  S[1]),  a1 = pack2bf(S[2],  S[3]);
            const unsigned b0 = pack2bf(S[4],  S[5]),  b1 = pack2bf(S[6],  S[7]);
            const unsigned c0 = pack2bf(S[8],  S[9]),  c1 = pack2bf(S[10], S[11]);
            const unsigned d0 = pack2bf(S[12], S[13]), d1 = pack2bf(S[14], S[15]);
            unsigned w0, w1, w2, w3, y0, y1, y2, y3;
            xpair(a0, b0, bpi, hi, w0, w2);   // bf1 words 0,2
            xpair(a1, b1, bpi, hi, w1, w3);   // bf1 words 1,3
            xpair(c0, d0, bpi, hi, y0, y2);   // bf2 words 0,2
            xpair(c1, d1, bpi, hi, y1, y3);   // bf2 words 1,3
            const u32x4 f1 = {w0, w1, w2, w3};
            const u32x4 f2 = {y0, y1, y2, y3};
            bf1 = __builtin_bit_cast(u16x8, f1);
            bf2 = __builtin_bit_cast(u16x8, f2);
        }
        __builtin_amdgcn_s_setprio(1);
        acc = mfma32(va0, bf1, acc);
        acc = mfma32(va1, bf2, acc);
        __builtin_amdgcn_s_setprio(0);

        // --- S1: kv [kv0+32, kv0+64) -> bf3 (g0+2), bf4 (g0+3) ---
        u16x8 bf3, bf4;
        {
            __builtin_amdgcn_s_setprio(1);
            f32x16 S = mfma32(nk1, uq, z16);
            __builtin_amdgcn_s_setprio(0);
            if (it < 7)
                nk1 = *reinterpret_cast<const u16x8*>(
                    Kp + (size_t)(kv0 + 96 + q32) * DK);
#pragma unroll
            for (int i = 0; i < 16; ++i) S[i] = exp2_(S[i]);
            const unsigned a0 = pack2bf(S[0],  S[1]),  a1 = pack2bf(S[2],  S[3]);
            const unsigned b0 = pack2bf(S[4],  S[5]),  b1 = pack2bf(S[6],  S[7]);
            const unsigned c0 = pack2bf(S[8],  S[9]),  c1 = pack2bf(S[10], S[11]);
            const unsigned d0 = pack2bf(S[12], S[13]), d1 = pack2bf(S[14], S[15]);
            unsigned w0, w1, w2, w3, y0, y1, y2, y3;
            xpair(a0, b0, bpi, hi, w0, w2);
            xpair(a1, b1, bpi, hi, w1, w3);
            xpair(c0, d0, bpi, hi, y0, y2);
            xpair(c1, d1, bpi, hi, y1, y3);
            const u32x4 f3 = {w0, w1, w2, w3};
            const u32x4 f4 = {y0, y1, y2, y3};
            bf3 = __builtin_bit_cast(u16x8, f3);
            bf4 = __builtin_bit_cast(u16x8, f4);
        }
        __builtin_amdgcn_s_setprio(1);
        acc = mfma32(va2, bf3, acc);
        acc = mfma32(va3, bf4, acc);
        __builtin_amdgcn_s_setprio(0);
    }

    // ---- 4-wave merge ----
    // acc layout: col q=q32; hi=0 regs: dk 0-3 (r0-3), dk 8-11 (r4-7), l (r8)
    //             hi=1 regs: dk 4-7 (r0-3), dk 12-15 (r4-7)
    float* Lsm = smem;            // [w][32]
    float* Osm = smem + 128;      // [w][q*20 + dk], w-stride 640
    float* Orow = Osm + w * 640 + q32 * 20;
    *reinterpret_cast<f32x4*>(Orow + (hi ? 4 : 0)) =
        f32x4{acc[0], acc[1], acc[2], acc[3]};
    *reinterpret_cast<f32x4*>(Orow + (hi ? 12 : 8)) =
        f32x4{acc[4], acc[5], acc[6], acc[7]};
    if (!hi) Lsm[w * 32 + q32] = acc[8];
    __syncthreads();

    const int q   = tid >> 3;              // 0..31
    const int dk2 = (tid & 7) * 2;         // 0,2,..,14
    const float l = Lsm[q] + Lsm[32 + q] + Lsm[64 + q] + Lsm[96 + q];
    const float* Oq = Osm + q * 20 + dk2;
    const float v0 = Oq[0] + Oq[640] + Oq[1280] + Oq[1920];
    const float v1 = Oq[1] + Oq[641] + Oq[1281] + Oq[1921];
    const float inv = 1.0f / l;
    *reinterpret_cast<unsigned int*>(
        AO + ((size_t)(b * NSEQ) + n0 + q) * DM + h * DK + dk2) =
        pack2bf(v0 * inv, v1 * inv);
}

// ---------------------------------------------------------------------------
// k_fc: C^T-form FC, output directly in (B, D, N).
// grid = b(4) x n-tile(128) x t-half(2), 4 waves, wave = one d'-tile.
// ---------------------------------------------------------------------------
__global__ __launch_bounds__(256) void k_fc(
    const unsigned short* __restrict__ AO,
    const unsigned short* __restrict__ WfcB, const float* __restrict__ bfc,
    float* __restrict__ out)
{
    const int lane = threadIdx.x & 63;
    const int w    = threadIdx.x >> 6;
    const int c    = lane & 15;
    const int quad = lane >> 4;
    const int b    = blockIdx.x >> 8;
    const int n0   = ((blockIdx.x >> 1) & 127) << 4;
    const int t    = (blockIdx.x & 1) * 4 + w;

    u16x8 af[4];
#pragma unroll
    for (int kk = 0; kk < 4; ++kk)
        af[kk] = *reinterpret_cast<const u16x8*>(
            AO + ((size_t)(b * NSEQ) + n0 + c) * DM + kk * 32 + quad * 8);

    f32x4 acc = {0.f, 0.f, 0.f, 0.f};
#pragma unroll
    for (int kk = 0; kk < 4; ++kk)
        acc = mfma16(*reinterpret_cast<const u16x8*>(
                         WfcB + (t * 16 + c) * DM + kk * 32 + quad * 8),
                     af[kk], acc);
#pragma unroll
    for (int r = 0; r < 4; ++r)
        out[(size_t)(b * DM + t * 16 + quad * 4 + r) * NSEQ + n0 + c] =
            acc[r] + bfc[t * 16 + quad * 4 + r];
}

// ---------------------------------------------------------------------------
extern "C" void kernel_launch(void* const* d_in, const int* in_sizes, int n_in,
                              void* d_out, int out_size, void* d_ws, size_t ws_size,
                              hipStream_t stream)
{
    const float* x    = (const float*)d_in[0];
    const float* mask = (const float*)d_in[1];
    const float* Wq   = (const float*)d_in[2];
    const float* bq   = (const float*)d_in[3];
    const float* Wk   = (const float*)d_in[4];
    const float* bk   = (const float*)d_in[5];
    const float* Wv   = (const float*)d_in[6];
    const float* bv   = (const float*)d_in[7];
    const float* Wfc  = (const float*)d_in[8];
    const float* bfc  = (const float*)d_in[9];
    float* out = (float*)d_out;

    const size_t QKV_ELEMS = (size_t)BSZ * NH * NSEQ * DK;  // 1,048,576
    unsigned short* Q    = (unsigned short*)d_ws;
    unsigned short* Kb   = Q + QKV_ELEMS;
    unsigned short* AO   = Kb + QKV_ELEMS;
    unsigned short* WfcB = AO + QKV_ELEMS;
    unsigned short* VW2  = WfcB + DM * DM;   // [bh][g=128][lane=64][8] bf16

    k_qkv<<<256, 768, 0, stream>>>(x, Wq, bq, Wk, bk, Wv, bv, Wfc, mask,
                                   Q, Kb, VW2, WfcB);
    k_attn<<<2048, 256, 0, stream>>>(Q, Kb, VW2, AO);
    k_fc<<<1024, 256, 0, stream>>>(AO, WfcB, bfc, out);
}

// Round 7
// 120.426 us; speedup vs baseline: 1.0800x; 1.0162x over previous
//
#include <hip/hip_runtime.h>
#include <stdint.h>

#define BSZ  4
#define NSEQ 2048
#define DM   128
#define NH   8
#define DK   16
#define LOG2E 1.4426950408889634f
// LOG2E / sqrt(128): folded into Wq/bq so scores exit QK^T in log2 domain
#define SCALE_QL 0.1275156338341935f
// mask weight: w = mask * 2^-18 (exact in bf16); folded into V' and the
// l-row of the PV A-tile. p = exp2(S) stays <= ~2^10, l ~ 1e-2 -> safe fp32.
#define W_SCALE 3.814697265625e-6f

typedef __bf16          bf16x8v __attribute__((ext_vector_type(8)));
typedef float           f32x4   __attribute__((ext_vector_type(4)));
typedef float           f32x16  __attribute__((ext_vector_type(16)));
typedef unsigned short  u16x8   __attribute__((ext_vector_type(8)));
typedef unsigned short  u16x4   __attribute__((ext_vector_type(4)));
typedef unsigned int    u32x2   __attribute__((ext_vector_type(2)));
typedef unsigned int    u32x4   __attribute__((ext_vector_type(4)));

__device__ __forceinline__ unsigned short f2bf(float f) {
    unsigned u = __float_as_uint(f);
    u = (u + 0x7fffu + ((u >> 16) & 1u)) >> 16;
    return (unsigned short)u;
}

__device__ __forceinline__ unsigned int pack2bf(float a, float b) {
#if __has_builtin(__builtin_amdgcn_cvt_pk_bf16_f32)
    typedef __bf16 bf16x2 __attribute__((ext_vector_type(2)));
    bf16x2 v = __builtin_amdgcn_cvt_pk_bf16_f32(a, b);
    return __builtin_bit_cast(unsigned int, v);
#else
    return (unsigned)f2bf(a) | ((unsigned)f2bf(b) << 16);
#endif
}

__device__ __forceinline__ float exp2_(float x) {
#if __has_builtin(__builtin_amdgcn_exp2f)
    return __builtin_amdgcn_exp2f(x);
#else
    return exp2f(x);
#endif
}

__device__ __forceinline__ f32x4 mfma16(u16x8 a, u16x8 b, f32x4 c) {
    return __builtin_amdgcn_mfma_f32_16x16x32_bf16(
        __builtin_bit_cast(bf16x8v, a), __builtin_bit_cast(bf16x8v, b), c, 0, 0, 0);
}
__device__ __forceinline__ f32x16 mfma32(u16x8 a, u16x8 b, f32x16 c) {
    return __builtin_amdgcn_mfma_f32_32x32x16_bf16(
        __builtin_bit_cast(bf16x8v, a), __builtin_bit_cast(bf16x8v, b), c, 0, 0, 0);
}

// Cross-half word exchange with UNAMBIGUOUS semantics (round-5 lesson).
// ds_bpermute is a pure pull: out[lane] = src[bpi>>2], full wave64.
// Pre-select halves the shuffle count: each lane SENDS the word its partner
// (lane^32) needs.  lo = this lane's low-kv word, hi_ = its high-kv word.
//   wA = fragment word for k-slots j=0,1  (hi=0: own lo ; hi=1: partner hi_)
//   wB = fragment word for k-slots j=4,5  (hi=0: partner lo ; hi=1: own hi_)
__device__ __forceinline__ void xpair(unsigned lo, unsigned hi_, int bpi, int isHi,
                                      unsigned& wA, unsigned& wB) {
    const unsigned send = isHi ? lo : hi_;
    const unsigned recv =
        (unsigned)__builtin_amdgcn_ds_bpermute(bpi, (int)send);
    wA = isHi ? recv : lo;
    wB = isHi ? hi_ : recv;
}

// ---------------------------------------------------------------------------
// k_prep: one-shot weight conversion + mask weave (round-6 theory: every
// k_qkv block re-converted W f32->bf16 redundantly — 2 strided loads + 12
// VALU per fragment x 16 frags x 12 waves x 256 blocks, duplicated again
// across nt pairs). Converts Wq (pre-scaled to log2 domain), Wk, Wv, Wfc
// to bf16 once, and weaves w = bf16(mask*2^-18) into VW2 row 16.
// grid = 96 x 256 covers 16384 W elems + 8192 mask elems.
// ---------------------------------------------------------------------------
__global__ __launch_bounds__(256) void k_prep(
    const float* __restrict__ Wq, const float* __restrict__ Wk,
    const float* __restrict__ Wv, const float* __restrict__ Wfc,
    const float* __restrict__ mask,
    unsigned short* __restrict__ WqB, unsigned short* __restrict__ WkB,
    unsigned short* __restrict__ WvB, unsigned short* __restrict__ WfcB,
    unsigned short* __restrict__ VW2)
{
    const int gt = blockIdx.x * 256 + threadIdx.x;
    if (gt < DM * DM) {
        WqB[gt]  = f2bf(Wq[gt] * SCALE_QL);
        WkB[gt]  = f2bf(Wk[gt]);
        WvB[gt]  = f2bf(Wv[gt]);
        WfcB[gt] = f2bf(Wfc[gt]);
    } else if (gt < DM * DM + BSZ * NSEQ) {
        const int i  = gt - DM * DM;          // i = b*NSEQ + kv
        const int kv = i & (NSEQ - 1);
        const int bb = i >> 11;
        const unsigned short w16 = f2bf(mask[i] * W_SCALE);
        unsigned short* dst = VW2 +
            (((size_t)(bb * NH) * 128 + (kv >> 4)) << 9) +
            (16 + ((kv >> 3) & 1) * 32) * 8 + (kv & 7);
#pragma unroll
        for (int hh = 0; hh < NH; ++hh)
            dst[(size_t)hh * 128 * 512] = w16;
    }
}

// ---------------------------------------------------------------------------
// k_qkv: C^T-form projection, x-tile staged in LDS (coalesced f32x4 loads).
// grid = b(4) x n-tile32(64), 768 threads = 12 waves = mat(3) x nsub(2) x th(2).
// W now pre-converted bf16 (k_prep): A-fragment = ONE 16 B load (was 2 f32x4
// loads + 8 muls + 4 cvt_pk). Q,K -> [B][H][N][16] bf16.
// V is emitted directly as the PV A-tile VW2[bh][g=kv/16][lane][8]:
//   lane = row + 32*khalf (khalf = bit3 of kv), row 0-15 = V'[dk] (V scaled
//   by w=mask*2^-18), row 16 = w (written by k_prep), rows 17-31 = garbage.
// ---------------------------------------------------------------------------
__global__ __launch_bounds__(768) void k_qkv(
    const float* __restrict__ x,
    const unsigned short* __restrict__ WqB, const float* __restrict__ bq,
    const unsigned short* __restrict__ WkB, const float* __restrict__ bk,
    const unsigned short* __restrict__ WvB, const float* __restrict__ bv,
    const float* __restrict__ mask,
    unsigned short* __restrict__ Q, unsigned short* __restrict__ Kb,
    unsigned short* __restrict__ VW2)
{
    __shared__ __align__(16) float xs[DM * 36];   // 32 n + 4 pad
    const int tid = threadIdx.x;

    const int b  = blockIdx.x >> 6;
    const int n0 = (blockIdx.x & 63) << 5;

    // stage x[b][0..128][n0..n0+32] -> xs[d*36 + j], fully coalesced
#pragma unroll
    for (int i = tid; i < 1024; i += 768) {
        const int d = i >> 3, c4 = (i & 7) << 2;
        *reinterpret_cast<f32x4*>(&xs[d * 36 + c4]) =
            *reinterpret_cast<const f32x4*>(x + (size_t)(b * DM + d) * NSEQ + n0 + c4);
    }
    __syncthreads();

    const int lane = tid & 63;
    const int wv   = tid >> 6;          // 0..11
    const int mat  = wv >> 2;           // 0..2
    const int nt   = (wv >> 1) & 1;     // n subtile
    const int th   = wv & 1;            // t half
    const int c    = lane & 15;
    const int quad = lane >> 4;
    const int col  = n0 + nt * 16 + c;

    // B-frag from LDS: B[k=d][n=c]
    u16x8 xf[4];
#pragma unroll
    for (int kk = 0; kk < 4; ++kk) {
        float f[8];
#pragma unroll
        for (int j = 0; j < 8; ++j)
            f[j] = xs[(kk * 32 + quad * 8 + j) * 36 + nt * 16 + c];
        u32x4 u = {pack2bf(f[0], f[1]), pack2bf(f[2], f[3]),
                   pack2bf(f[4], f[5]), pack2bf(f[6], f[7])};
        xf[kk] = __builtin_bit_cast(u16x8, u);
    }

    const unsigned short* W = (mat == 0) ? WqB : (mat == 1) ? WkB : WvB;
    const float* bias = (mat == 0) ? bq : (mat == 1) ? bk : bv;
    const float  sc   = (mat == 0) ? SCALE_QL : 1.0f;   // bias scale only
    // V' scale: w = mask * 2^-18 for this column
    const float  vwsc = (mat == 2) ? mask[b * NSEQ + col] * W_SCALE : 0.f;
    const int    g    = col >> 4;
    const int    roff = ((col >> 3) & 1) * 32;
    const int    j7   = col & 7;

#pragma unroll
    for (int tt = 0; tt < 4; ++tt) {
        const int t = th * 4 + tt;
        f32x4 acc = {0.f, 0.f, 0.f, 0.f};
#pragma unroll
        for (int kk = 0; kk < 4; ++kk)
            acc = mfma16(*reinterpret_cast<const u16x8*>(
                             W + (t * 16 + c) * DM + kk * 32 + quad * 8),
                         xf[kk], acc);
        if (mat == 2) {
            unsigned short* vwp = VW2 +
                (((size_t)((b * NH + t) * 128 + g)) << 9) + j7;
#pragma unroll
            for (int r = 0; r < 4; ++r)
                vwp[(quad * 4 + r + roff) * 8] =
                    f2bf((acc[r] + bias[t * 16 + quad * 4 + r]) * vwsc);
        } else {
            u16x4 pk;
#pragma unroll
            for (int r = 0; r < 4; ++r)
                pk[r] = f2bf(acc[r] + bias[t * 16 + quad * 4 + r] * sc);
            *reinterpret_cast<u16x4*>(
                (mat == 0 ? Q : Kb) + ((size_t)(b * NH + t) * NSEQ + col) * DK +
                quad * 4) = pk;
        }
    }
}

// ---------------------------------------------------------------------------
// k_attn: fixed-scale flash attention, ZERO LDS data staging in the main
// loop (round-4 finding: the LDS transpose round-trip serialized the
// dominant VALU/trans pipe). S = mfma32(K, Q) leaves, on lane (q=l&31,
// hi=l>>5), p[kvl] for kvl=(reg&3)+8*(reg>>2)+4*hi. The PV B-frag
// (B[k=8*hi+j][n=q]) is built IN REGISTERS: cvt_pk pairs, then one
// ds_bpermute(lane^32) per word-pair via xpair. PV is mfma32 with A = VW2
// tile: rows 0-15 = V', row 16 = w -> l falls out of the same MFMA (C row
// 16, reg 8 on hi=0 lanes); rows 17-31 garbage (C rows never read).
// LDS (10.8 KB) only for the epilogue merge.
// XCD-chunked bid swizzle (round-3: FETCH 17.5 -> 3.1 MB).
// __launch_bounds__(256,4): proven no-spill regime. FROZEN since round 6
// (passing, ~36 us).
// ---------------------------------------------------------------------------
__global__ __launch_bounds__(256, 4) void k_attn(
    const unsigned short* __restrict__ Q,
    const unsigned short* __restrict__ Kb,
    const unsigned short* __restrict__ VW2,
    unsigned short* __restrict__ AO)
{
    __shared__ __align__(16) float smem[128 + 4 * 32 * 20];  // Lsm + Osm
    const int tid  = threadIdx.x;
    const int lane = tid & 63;
    const int w    = tid >> 6;      // kv quarter
    const int q32  = lane & 31;
    const int hi   = lane >> 5;
    const int bpi  = (lane ^ 32) << 2;   // bpermute partner index (bytes)

    // XCD-chunked swizzle: hw round-robins bid%8 across XCDs; give each XCD
    // a contiguous 256-block logical chunk (= 4 complete (b,h) groups).
    const int bid = ((int)blockIdx.x & 7) * 256 + ((int)blockIdx.x >> 3);
    const int b  = bid >> 9;
    const int h  = (bid >> 6) & 7;
    const int n0 = (bid & 63) << 5;
    const int bh = b * NH + h;

    // Q B-frag (prescaled to log2 domain): B[k=8*hi+j][n=q32]
    const u16x8 uq = *reinterpret_cast<const u16x8*>(
        Q + ((size_t)bh * NSEQ + n0 + q32) * DK + 8 * hi);

    const unsigned short* Kp = Kb + (size_t)bh * NSEQ * DK + 8 * hi;
    // PV A-tile: lane-linear, 16 B/lane fully coalesced
    const unsigned short* Ap = VW2 + (((size_t)bh * 128) << 9) + lane * 8;

    f32x16 acc = {};                  // O^T rows 0-15, l at row 16
    const f32x16 z16 = {};
    const int kvb = w * (NSEQ / 4);

    // prefetch iteration 0's K fragments
    u16x8 nk0 = *reinterpret_cast<const u16x8*>(Kp + (size_t)(kvb + q32) * DK);
    u16x8 nk1 = *reinterpret_cast<const u16x8*>(Kp + (size_t)(kvb + 32 + q32) * DK);

#pragma unroll 1
    for (int it = 0; it < 8; ++it) {
        const int kv0 = kvb + it * 64;
        const int g0  = kv0 >> 4;
        // PV A-frags for this iter's 4 K=16 tiles (L2-resident, issued early)
        const u16x8 va0 = *reinterpret_cast<const u16x8*>(Ap + ((size_t)(g0    ) << 9));
        const u16x8 va1 = *reinterpret_cast<const u16x8*>(Ap + ((size_t)(g0 + 1) << 9));
        const u16x8 va2 = *reinterpret_cast<const u16x8*>(Ap + ((size_t)(g0 + 2) << 9));
        const u16x8 va3 = *reinterpret_cast<const u16x8*>(Ap + ((size_t)(g0 + 3) << 9));

        // --- S0: kv [kv0, kv0+32) -> bf1 (group g0), bf2 (group g0+1) ---
        u16x8 bf1, bf2;
        {
            __builtin_amdgcn_s_setprio(1);
            f32x16 S = mfma32(nk0, uq, z16);   // S^T[kv][q] (log2 domain)
            __builtin_amdgcn_s_setprio(0);
            if (it < 7)
                nk0 = *reinterpret_cast<const u16x8*>(
                    Kp + (size_t)(kv0 + 64 + q32) * DK);
#pragma unroll
            for (int i = 0; i < 16; ++i) S[i] = exp2_(S[i]);
            // packed words; own kv = (pairs) 0,1|2,3 (+4*hi) etc.
            const unsigned a0 = pack2bf(S[0],  S[1]),  a1 = pack2bf(S[2],  S[3]);
            const unsigned b0 = pack2bf(S[4],  S[5]),  b1 = pack2bf(S[6],  S[7]);
            const unsigned c0 = pack2bf(S[8],  S[9]),  c1 = pack2bf(S[10], S[11]);
            const unsigned d0 = pack2bf(S[12], S[13]), d1 = pack2bf(S[14], S[15]);
            unsigned w0, w1, w2, w3, y0, y1, y2, y3;
            xpair(a0, b0, bpi, hi, w0, w2);   // bf1 words 0,2
            xpair(a1, b1, bpi, hi, w1, w3);   // bf1 words 1,3
            xpair(c0, d0, bpi, hi, y0, y2);   // bf2 words 0,2
            xpair(c1, d1, bpi, hi, y1, y3);   // bf2 words 1,3
            const u32x4 f1 = {w0, w1, w2, w3};
            const u32x4 f2 = {y0, y1, y2, y3};
            bf1 = __builtin_bit_cast(u16x8, f1);
            bf2 = __builtin_bit_cast(u16x8, f2);
        }
        __builtin_amdgcn_s_setprio(1);
        acc = mfma32(va0, bf1, acc);
        acc = mfma32(va1, bf2, acc);
        __builtin_amdgcn_s_setprio(0);

        // --- S1: kv [kv0+32, kv0+64) -> bf3 (g0+2), bf4 (g0+3) ---
        u16x8 bf3, bf4;
        {
            __builtin_amdgcn_s_setprio(1);
            f32x16 S = mfma32(nk1, uq, z16);
            __builtin_amdgcn_s_setprio(0);
            if (it < 7)
                nk1 = *reinterpret_cast<const u16x8*>(
                    Kp + (size_t)(kv0 + 96 + q32) * DK);
#pragma unroll
            for (int i = 0; i < 16; ++i) S[i] = exp2_(S[i]);
            const unsigned a0 = pack2bf(S[0],  S[1]),  a1 = pack2bf(S[2],  S[3]);
            const unsigned b0 = pack2bf(S[4],  S[5]),  b1 = pack2bf(S[6],  S[7]);
            const unsigned c0 = pack2bf(S[8],  S[9]),  c1 = pack2bf(S[10], S[11]);
            const unsigned d0 = pack2bf(S[12], S[13]), d1 = pack2bf(S[14], S[15]);
            unsigned w0, w1, w2, w3, y0, y1, y2, y3;
            xpair(a0, b0, bpi, hi, w0, w2);
            xpair(a1, b1, bpi, hi, w1, w3);
            xpair(c0, d0, bpi, hi, y0, y2);
            xpair(c1, d1, bpi, hi, y1, y3);
            const u32x4 f3 = {w0, w1, w2, w3};
            const u32x4 f4 = {y0, y1, y2, y3};
            bf3 = __builtin_bit_cast(u16x8, f3);
            bf4 = __builtin_bit_cast(u16x8, f4);
        }
        __builtin_amdgcn_s_setprio(1);
        acc = mfma32(va2, bf3, acc);
        acc = mfma32(va3, bf4, acc);
        __builtin_amdgcn_s_setprio(0);
    }

    // ---- 4-wave merge ----
    // acc layout: col q=q32; hi=0 regs: dk 0-3 (r0-3), dk 8-11 (r4-7), l (r8)
    //             hi=1 regs: dk 4-7 (r0-3), dk 12-15 (r4-7)
    float* Lsm = smem;            // [w][32]
    float* Osm = smem + 128;      // [w][q*20 + dk], w-stride 640
    float* Orow = Osm + w * 640 + q32 * 20;
    *reinterpret_cast<f32x4*>(Orow + (hi ? 4 : 0)) =
        f32x4{acc[0], acc[1], acc[2], acc[3]};
    *reinterpret_cast<f32x4*>(Orow + (hi ? 12 : 8)) =
        f32x4{acc[4], acc[5], acc[6], acc[7]};
    if (!hi) Lsm[w * 32 + q32] = acc[8];
    __syncthreads();

    const int q   = tid >> 3;              // 0..31
    const int dk2 = (tid & 7) * 2;         // 0,2,..,14
    const float l = Lsm[q] + Lsm[32 + q] + Lsm[64 + q] + Lsm[96 + q];
    const float* Oq = Osm + q * 20 + dk2;
    const float v0 = Oq[0] + Oq[640] + Oq[1280] + Oq[1920];
    const float v1 = Oq[1] + Oq[641] + Oq[1281] + Oq[1921];
    const float inv = 1.0f / l;
    *reinterpret_cast<unsigned int*>(
        AO + ((size_t)(b * NSEQ) + n0 + q) * DM + h * DK + dk2) =
        pack2bf(v0 * inv, v1 * inv);
}

// ---------------------------------------------------------------------------
// k_fc: C^T-form FC, output directly in (B, D, N).
// grid = b(4) x n-tile(128) x t-half(2), 4 waves, wave = one d'-tile.
// ---------------------------------------------------------------------------
__global__ __launch_bounds__(256) void k_fc(
    const unsigned short* __restrict__ AO,
    const unsigned short* __restrict__ WfcB, const float* __restrict__ bfc,
    float* __restrict__ out)
{
    const int lane = threadIdx.x & 63;
    const int w    = threadIdx.x >> 6;
    const int c    = lane & 15;
    const int quad = lane >> 4;
    const int b    = blockIdx.x >> 8;
    const int n0   = ((blockIdx.x >> 1) & 127) << 4;
    const int t    = (blockIdx.x & 1) * 4 + w;

    u16x8 af[4];
#pragma unroll
    for (int kk = 0; kk < 4; ++kk)
        af[kk] = *reinterpret_cast<const u16x8*>(
            AO + ((size_t)(b * NSEQ) + n0 + c) * DM + kk * 32 + quad * 8);

    f32x4 acc = {0.f, 0.f, 0.f, 0.f};
#pragma unroll
    for (int kk = 0; kk < 4; ++kk)
        acc = mfma16(*reinterpret_cast<const u16x8*>(
                         WfcB + (t * 16 + c) * DM + kk * 32 + quad * 8),
                     af[kk], acc);
#pragma unroll
    for (int r = 0; r < 4; ++r)
        out[(size_t)(b * DM + t * 16 + quad * 4 + r) * NSEQ + n0 + c] =
            acc[r] + bfc[t * 16 + quad * 4 + r];
}

// ---------------------------------------------------------------------------
extern "C" void kernel_launch(void* const* d_in, const int* in_sizes, int n_in,
                              void* d_out, int out_size, void* d_ws, size_t ws_size,
                              hipStream_t stream)
{
    const float* x    = (const float*)d_in[0];
    const float* mask = (const float*)d_in[1];
    const float* Wq   = (const float*)d_in[2];
    const float* bq   = (const float*)d_in[3];
    const float* Wk   = (const float*)d_in[4];
    const float* bk   = (const float*)d_in[5];
    const float* Wv   = (const float*)d_in[6];
    const float* bv   = (const float*)d_in[7];
    const float* Wfc  = (const float*)d_in[8];
    const float* bfc  = (const float*)d_in[9];
    float* out = (float*)d_out;

    const size_t QKV_ELEMS = (size_t)BSZ * NH * NSEQ * DK;  // 1,048,576
    unsigned short* Q    = (unsigned short*)d_ws;
    unsigned short* Kb   = Q + QKV_ELEMS;
    unsigned short* AO   = Kb + QKV_ELEMS;
    unsigned short* WfcB = AO + QKV_ELEMS;
    unsigned short* VW2  = WfcB + DM * DM;   // [bh][g=128][lane=64][8] bf16
    unsigned short* WqB  = VW2 + (size_t)BSZ * NH * 128 * 512;
    unsigned short* WkB  = WqB + DM * DM;
    unsigned short* WvB  = WkB + DM * DM;

    k_prep<<<96, 256, 0, stream>>>(Wq, Wk, Wv, Wfc, mask,
                                   WqB, WkB, WvB, WfcB, VW2);
    k_qkv<<<256, 768, 0, stream>>>(x, WqB, bq, WkB, bk, WvB, bv, mask,
                                   Q, Kb, VW2);
    k_attn<<<2048, 256, 0, stream>>>(Q, Kb, VW2, AO);
    k_fc<<<1024, 256, 0, stream>>>(AO, WfcB, bfc, out);
}

// Round 8
// 118.255 us; speedup vs baseline: 1.0998x; 1.0184x over previous
//
#include <hip/hip_runtime.h>
#include <stdint.h>

#define BSZ  4
#define NSEQ 2048
#define DM   128
#define NH   8
#define DK   16
#define LOG2E 1.4426950408889634f
// LOG2E / sqrt(128): folded into Wq/bq so scores exit QK^T in log2 domain
#define SCALE_QL 0.1275156338341935f
// mask weight: w = mask * 2^-18 (exact in bf16); folded into V' and the
// l-row of the PV A-tile. p = exp2(S) stays <= ~2^10, l ~ 1e-2 -> safe fp32.
#define W_SCALE 3.814697265625e-6f

typedef __bf16          bf16x8v __attribute__((ext_vector_type(8)));
typedef float           f32x4   __attribute__((ext_vector_type(4)));
typedef float           f32x16  __attribute__((ext_vector_type(16)));
typedef unsigned short  u16x8   __attribute__((ext_vector_type(8)));
typedef unsigned short  u16x4   __attribute__((ext_vector_type(4)));
typedef unsigned int    u32x2   __attribute__((ext_vector_type(2)));
typedef unsigned int    u32x4   __attribute__((ext_vector_type(4)));

__device__ __forceinline__ unsigned short f2bf(float f) {
    unsigned u = __float_as_uint(f);
    u = (u + 0x7fffu + ((u >> 16) & 1u)) >> 16;
    return (unsigned short)u;
}

__device__ __forceinline__ unsigned int pack2bf(float a, float b) {
#if __has_builtin(__builtin_amdgcn_cvt_pk_bf16_f32)
    typedef __bf16 bf16x2 __attribute__((ext_vector_type(2)));
    bf16x2 v = __builtin_amdgcn_cvt_pk_bf16_f32(a, b);
    return __builtin_bit_cast(unsigned int, v);
#else
    return (unsigned)f2bf(a) | ((unsigned)f2bf(b) << 16);
#endif
}

__device__ __forceinline__ float exp2_(float x) {
#if __has_builtin(__builtin_amdgcn_exp2f)
    return __builtin_amdgcn_exp2f(x);
#else
    return exp2f(x);
#endif
}

__device__ __forceinline__ f32x4 mfma16(u16x8 a, u16x8 b, f32x4 c) {
    return __builtin_amdgcn_mfma_f32_16x16x32_bf16(
        __builtin_bit_cast(bf16x8v, a), __builtin_bit_cast(bf16x8v, b), c, 0, 0, 0);
}
__device__ __forceinline__ f32x16 mfma32(u16x8 a, u16x8 b, f32x16 c) {
    return __builtin_amdgcn_mfma_f32_32x32x16_bf16(
        __builtin_bit_cast(bf16x8v, a), __builtin_bit_cast(bf16x8v, b), c, 0, 0, 0);
}

// Cross-half word exchange with UNAMBIGUOUS semantics (round-5 lesson).
// ds_bpermute is a pure pull: out[lane] = src[bpi>>2], full wave64.
// Pre-select halves the shuffle count: each lane SENDS the word its partner
// (lane^32) needs.  lo = this lane's low-kv word, hi_ = its high-kv word.
//   wA = fragment word for k-slots j=0,1  (hi=0: own lo ; hi=1: partner hi_)
//   wB = fragment word for k-slots j=4,5  (hi=0: partner lo ; hi=1: own hi_)
__device__ __forceinline__ void xpair(unsigned lo, unsigned hi_, int bpi, int isHi,
                                      unsigned& wA, unsigned& wB) {
    const unsigned send = isHi ? lo : hi_;
    const unsigned recv =
        (unsigned)__builtin_amdgcn_ds_bpermute(bpi, (int)send);
    wA = isHi ? recv : lo;
    wB = isHi ? hi_ : recv;
}

// build PV B-frags (two K=16 groups) from one S tile (post-exp2, packed)
__device__ __forceinline__ void build_bfrags(const f32x16& S, int bpi, int hi,
                                             u16x8& bfe, u16x8& bfo) {
    const unsigned a0 = pack2bf(S[0],  S[1]),  a1 = pack2bf(S[2],  S[3]);
    const unsigned b0 = pack2bf(S[4],  S[5]),  b1 = pack2bf(S[6],  S[7]);
    const unsigned c0 = pack2bf(S[8],  S[9]),  c1 = pack2bf(S[10], S[11]);
    const unsigned d0 = pack2bf(S[12], S[13]), d1 = pack2bf(S[14], S[15]);
    unsigned w0, w1, w2, w3, y0, y1, y2, y3;
    xpair(a0, b0, bpi, hi, w0, w2);
    xpair(a1, b1, bpi, hi, w1, w3);
    xpair(c0, d0, bpi, hi, y0, y2);
    xpair(c1, d1, bpi, hi, y1, y3);
    const u32x4 f1 = {w0, w1, w2, w3};
    const u32x4 f2 = {y0, y1, y2, y3};
    bfe = __builtin_bit_cast(u16x8, f1);
    bfo = __builtin_bit_cast(u16x8, f2);
}

// ---------------------------------------------------------------------------
// k_prep: one-shot weight conversion + mask weave. Converts Wq (pre-scaled
// to log2 domain), Wk, Wv, Wfc to bf16 once, and weaves w = bf16(mask*2^-18)
// into VW2 row 16. grid = 96 x 256.
// ---------------------------------------------------------------------------
__global__ __launch_bounds__(256) void k_prep(
    const float* __restrict__ Wq, const float* __restrict__ Wk,
    const float* __restrict__ Wv, const float* __restrict__ Wfc,
    const float* __restrict__ mask,
    unsigned short* __restrict__ WqB, unsigned short* __restrict__ WkB,
    unsigned short* __restrict__ WvB, unsigned short* __restrict__ WfcB,
    unsigned short* __restrict__ VW2)
{
    const int gt = blockIdx.x * 256 + threadIdx.x;
    if (gt < DM * DM) {
        WqB[gt]  = f2bf(Wq[gt] * SCALE_QL);
        WkB[gt]  = f2bf(Wk[gt]);
        WvB[gt]  = f2bf(Wv[gt]);
        WfcB[gt] = f2bf(Wfc[gt]);
    } else if (gt < DM * DM + BSZ * NSEQ) {
        const int i  = gt - DM * DM;          // i = b*NSEQ + kv
        const int kv = i & (NSEQ - 1);
        const int bb = i >> 11;
        const unsigned short w16 = f2bf(mask[i] * W_SCALE);
        unsigned short* dst = VW2 +
            (((size_t)(bb * NH) * 128 + (kv >> 4)) << 9) +
            (16 + ((kv >> 3) & 1) * 32) * 8 + (kv & 7);
#pragma unroll
        for (int hh = 0; hh < NH; ++hh)
            dst[(size_t)hh * 128 * 512] = w16;
    }
}

// ---------------------------------------------------------------------------
// k_qkv: C^T-form projection, x-tile staged in LDS (coalesced f32x4 loads).
// grid = b(4) x n-tile32(64), 768 threads = 12 waves = mat(3) x nsub(2) x th(2).
// W pre-converted bf16 (k_prep). Q,K -> [B][H][N][16] bf16.
// V is emitted directly as the PV A-tile VW2[bh][g=kv/16][lane][8]:
//   lane = row + 32*khalf (khalf = bit3 of kv), row 0-15 = V'[dk] (V scaled
//   by w=mask*2^-18), row 16 = w (written by k_prep), rows 17-31 = garbage.
// ---------------------------------------------------------------------------
__global__ __launch_bounds__(768) void k_qkv(
    const float* __restrict__ x,
    const unsigned short* __restrict__ WqB, const float* __restrict__ bq,
    const unsigned short* __restrict__ WkB, const float* __restrict__ bk,
    const unsigned short* __restrict__ WvB, const float* __restrict__ bv,
    const float* __restrict__ mask,
    unsigned short* __restrict__ Q, unsigned short* __restrict__ Kb,
    unsigned short* __restrict__ VW2)
{
    __shared__ __align__(16) float xs[DM * 36];   // 32 n + 4 pad
    const int tid = threadIdx.x;

    const int b  = blockIdx.x >> 6;
    const int n0 = (blockIdx.x & 63) << 5;

    // stage x[b][0..128][n0..n0+32] -> xs[d*36 + j], fully coalesced
#pragma unroll
    for (int i = tid; i < 1024; i += 768) {
        const int d = i >> 3, c4 = (i & 7) << 2;
        *reinterpret_cast<f32x4*>(&xs[d * 36 + c4]) =
            *reinterpret_cast<const f32x4*>(x + (size_t)(b * DM + d) * NSEQ + n0 + c4);
    }
    __syncthreads();

    const int lane = tid & 63;
    const int wv   = tid >> 6;          // 0..11
    const int mat  = wv >> 2;           // 0..2
    const int nt   = (wv >> 1) & 1;     // n subtile
    const int th   = wv & 1;            // t half
    const int c    = lane & 15;
    const int quad = lane >> 4;
    const int col  = n0 + nt * 16 + c;

    // B-frag from LDS: B[k=d][n=c]
    u16x8 xf[4];
#pragma unroll
    for (int kk = 0; kk < 4; ++kk) {
        float f[8];
#pragma unroll
        for (int j = 0; j < 8; ++j)
            f[j] = xs[(kk * 32 + quad * 8 + j) * 36 + nt * 16 + c];
        u32x4 u = {pack2bf(f[0], f[1]), pack2bf(f[2], f[3]),
                   pack2bf(f[4], f[5]), pack2bf(f[6], f[7])};
        xf[kk] = __builtin_bit_cast(u16x8, u);
    }

    const unsigned short* W = (mat == 0) ? WqB : (mat == 1) ? WkB : WvB;
    const float* bias = (mat == 0) ? bq : (mat == 1) ? bk : bv;
    const float  sc   = (mat == 0) ? SCALE_QL : 1.0f;   // bias scale only
    // V' scale: w = mask * 2^-18 for this column
    const float  vwsc = (mat == 2) ? mask[b * NSEQ + col] * W_SCALE : 0.f;
    const int    g    = col >> 4;
    const int    roff = ((col >> 3) & 1) * 32;
    const int    j7   = col & 7;

#pragma unroll
    for (int tt = 0; tt < 4; ++tt) {
        const int t = th * 4 + tt;
        f32x4 acc = {0.f, 0.f, 0.f, 0.f};
#pragma unroll
        for (int kk = 0; kk < 4; ++kk)
            acc = mfma16(*reinterpret_cast<const u16x8*>(
                             W + (t * 16 + c) * DM + kk * 32 + quad * 8),
                         xf[kk], acc);
        if (mat == 2) {
            unsigned short* vwp = VW2 +
                (((size_t)((b * NH + t) * 128 + g)) << 9) + j7;
#pragma unroll
            for (int r = 0; r < 4; ++r)
                vwp[(quad * 4 + r + roff) * 8] =
                    f2bf((acc[r] + bias[t * 16 + quad * 4 + r]) * vwsc);
        } else {
            u16x4 pk;
#pragma unroll
            for (int r = 0; r < 4; ++r)
                pk[r] = f2bf(acc[r] + bias[t * 16 + quad * 4 + r] * sc);
            *reinterpret_cast<u16x4*>(
                (mat == 0 ? Q : Kb) + ((size_t)(b * NH + t) * NSEQ + col) * DK +
                quad * 4) = pk;
        }
    }
}

// ---------------------------------------------------------------------------
// k_attn: fixed-scale flash attention, register-resident (no LDS staging).
// ROUND-8 CHANGE: TWO query-tiles per block (n-tile64). Grid 2048 -> 1024
// (= exactly 4 blocks/CU, one round). Both S-streams share nk and va:
// K/V L2 traffic halves (400 -> 200 MB), and the two independent
// MFMA->exp2->pack->bpermute->PV chains give the scheduler ILP at every
// stall point (round-4/7 finding: latency-bound at 4 waves/SIMD, ~60% of
// time with no VALU issue; TLP is reg-capped per round 2). Per-stream acc
// dependency chain also halves (4 not 8 dependent mfma32/iter).
// All HW-validated layouts unchanged: S = mfma32(K,Q) lane mapping,
// xpair shuffle, VW2 A-tile (rows 0-15 V', row 16 w -> l in C row 16).
// LDS (21.5 KB) only for the epilogue merge.
// __launch_bounds__(256,4): proven no-spill regime; tripwire WRITE_SIZE.
// ---------------------------------------------------------------------------
__global__ __launch_bounds__(256, 4) void k_attn(
    const unsigned short* __restrict__ Q,
    const unsigned short* __restrict__ Kb,
    const unsigned short* __restrict__ VW2,
    unsigned short* __restrict__ AO)
{
    __shared__ __align__(16) float smem[256 + 2 * 4 * 32 * 20];  // Lsm + Osm
    const int tid  = threadIdx.x;
    const int lane = tid & 63;
    const int w    = tid >> 6;      // kv quarter
    const int q32  = lane & 31;
    const int hi   = lane >> 5;
    const int bpi  = (lane ^ 32) << 2;   // bpermute partner index (bytes)

    // XCD-chunked swizzle: 1024 blocks -> 128-block chunk per XCD
    // (= 4 complete (b,h) groups of 32 blocks each).
    const int bid = ((int)blockIdx.x & 7) * 128 + ((int)blockIdx.x >> 3);
    const int b  = bid >> 8;
    const int h  = (bid >> 5) & 7;
    const int n0 = (bid & 31) << 6;     // 64-query tile
    const int bh = b * NH + h;

    // Q B-frags for the two 32-query sub-tiles (prescaled to log2 domain)
    const u16x8 uqA = *reinterpret_cast<const u16x8*>(
        Q + ((size_t)bh * NSEQ + n0 + q32) * DK + 8 * hi);
    const u16x8 uqB = *reinterpret_cast<const u16x8*>(
        Q + ((size_t)bh * NSEQ + n0 + 32 + q32) * DK + 8 * hi);

    const unsigned short* Kp = Kb + (size_t)bh * NSEQ * DK + 8 * hi;
    // PV A-tile: lane-linear, 16 B/lane fully coalesced
    const unsigned short* Ap = VW2 + (((size_t)bh * 128) << 9) + lane * 8;

    f32x16 accA = {};                 // O^T rows 0-15, l at row 16 (tile A)
    f32x16 accB = {};                 // (tile B)
    const f32x16 z16 = {};
    const int kvb = w * (NSEQ / 4);

    // prefetch iteration 0's K fragments
    u16x8 nk0 = *reinterpret_cast<const u16x8*>(Kp + (size_t)(kvb + q32) * DK);
    u16x8 nk1 = *reinterpret_cast<const u16x8*>(Kp + (size_t)(kvb + 32 + q32) * DK);

#pragma unroll 1
    for (int it = 0; it < 8; ++it) {
        const int kv0 = kvb + it * 64;
        const int g0  = kv0 >> 4;
        // PV A-frags for this iter's 4 K=16 tiles (L2-resident, shared A/B)
        const u16x8 va0 = *reinterpret_cast<const u16x8*>(Ap + ((size_t)(g0    ) << 9));
        const u16x8 va1 = *reinterpret_cast<const u16x8*>(Ap + ((size_t)(g0 + 1) << 9));
        const u16x8 va2 = *reinterpret_cast<const u16x8*>(Ap + ((size_t)(g0 + 2) << 9));
        const u16x8 va3 = *reinterpret_cast<const u16x8*>(Ap + ((size_t)(g0 + 3) << 9));

        // --- kv [kv0, kv0+32): two independent S-streams off nk0 ---
        {
            __builtin_amdgcn_s_setprio(1);
            f32x16 SA = mfma32(nk0, uqA, z16);   // S^T[kv][q] (log2 domain)
            f32x16 SB = mfma32(nk0, uqB, z16);
            __builtin_amdgcn_s_setprio(0);
            if (it < 7)
                nk0 = *reinterpret_cast<const u16x8*>(
                    Kp + (size_t)(kv0 + 64 + q32) * DK);
#pragma unroll
            for (int i = 0; i < 16; ++i) SA[i] = exp2_(SA[i]);
#pragma unroll
            for (int i = 0; i < 16; ++i) SB[i] = exp2_(SB[i]);
            u16x8 bfA1, bfA2, bfB1, bfB2;
            build_bfrags(SA, bpi, hi, bfA1, bfA2);
            build_bfrags(SB, bpi, hi, bfB1, bfB2);
            __builtin_amdgcn_s_setprio(1);
            accA = mfma32(va0, bfA1, accA);
            accB = mfma32(va0, bfB1, accB);
            accA = mfma32(va1, bfA2, accA);
            accB = mfma32(va1, bfB2, accB);
            __builtin_amdgcn_s_setprio(0);
        }

        // --- kv [kv0+32, kv0+64): same off nk1 ---
        {
            __builtin_amdgcn_s_setprio(1);
            f32x16 SA = mfma32(nk1, uqA, z16);
            f32x16 SB = mfma32(nk1, uqB, z16);
            __builtin_amdgcn_s_setprio(0);
            if (it < 7)
                nk1 = *reinterpret_cast<const u16x8*>(
                    Kp + (size_t)(kv0 + 96 + q32) * DK);
#pragma unroll
            for (int i = 0; i < 16; ++i) SA[i] = exp2_(SA[i]);
#pragma unroll
            for (int i = 0; i < 16; ++i) SB[i] = exp2_(SB[i]);
            u16x8 bfA1, bfA2, bfB1, bfB2;
            build_bfrags(SA, bpi, hi, bfA1, bfA2);
            build_bfrags(SB, bpi, hi, bfB1, bfB2);
            __builtin_amdgcn_s_setprio(1);
            accA = mfma32(va2, bfA1, accA);
            accB = mfma32(va2, bfB1, accB);
            accA = mfma32(va3, bfA2, accA);
            accB = mfma32(va3, bfB2, accB);
            __builtin_amdgcn_s_setprio(0);
        }
    }

    // ---- 4-wave merge, two tiles ----
    // acc layout: col q=q32; hi=0 regs: dk 0-3 (r0-3), dk 8-11 (r4-7), l (r8)
    //             hi=1 regs: dk 4-7 (r0-3), dk 12-15 (r4-7)
    float* Lsm = smem;            // [t2][w][32]
    float* Osm = smem + 256;      // [t2][w][q*20 + dk], tile stride 2560
    {
        float* Orow = Osm + w * 640 + q32 * 20;
        *reinterpret_cast<f32x4*>(Orow + (hi ? 4 : 0)) =
            f32x4{accA[0], accA[1], accA[2], accA[3]};
        *reinterpret_cast<f32x4*>(Orow + (hi ? 12 : 8)) =
            f32x4{accA[4], accA[5], accA[6], accA[7]};
        if (!hi) Lsm[w * 32 + q32] = accA[8];
        float* Orow2 = Orow + 2560;
        *reinterpret_cast<f32x4*>(Orow2 + (hi ? 4 : 0)) =
            f32x4{accB[0], accB[1], accB[2], accB[3]};
        *reinterpret_cast<f32x4*>(Orow2 + (hi ? 12 : 8)) =
            f32x4{accB[4], accB[5], accB[6], accB[7]};
        if (!hi) Lsm[128 + w * 32 + q32] = accB[8];
    }
    __syncthreads();

    const int q   = tid >> 3;              // 0..31
    const int dk2 = (tid & 7) * 2;         // 0,2,..,14
#pragma unroll
    for (int t2 = 0; t2 < 2; ++t2) {
        const float* Lt = Lsm + t2 * 128;
        const float l = Lt[q] + Lt[32 + q] + Lt[64 + q] + Lt[96 + q];
        const float* Oq = Osm + t2 * 2560 + q * 20 + dk2;
        const float v0 = Oq[0] + Oq[640] + Oq[1280] + Oq[1920];
        const float v1 = Oq[1] + Oq[641] + Oq[1281] + Oq[1921];
        const float inv = 1.0f / l;
        *reinterpret_cast<unsigned int*>(
            AO + ((size_t)(b * NSEQ) + n0 + t2 * 32 + q) * DM + h * DK + dk2) =
            pack2bf(v0 * inv, v1 * inv);
    }
}

// ---------------------------------------------------------------------------
// k_fc: C^T-form FC, output directly in (B, D, N).
// grid = b(4) x n-tile(128) x t-half(2), 4 waves, wave = one d'-tile.
// ---------------------------------------------------------------------------
__global__ __launch_bounds__(256) void k_fc(
    const unsigned short* __restrict__ AO,
    const unsigned short* __restrict__ WfcB, const float* __restrict__ bfc,
    float* __restrict__ out)
{
    const int lane = threadIdx.x & 63;
    const int w    = threadIdx.x >> 6;
    const int c    = lane & 15;
    const int quad = lane >> 4;
    const int b    = blockIdx.x >> 8;
    const int n0   = ((blockIdx.x >> 1) & 127) << 4;
    const int t    = (blockIdx.x & 1) * 4 + w;

    u16x8 af[4];
#pragma unroll
    for (int kk = 0; kk < 4; ++kk)
        af[kk] = *reinterpret_cast<const u16x8*>(
            AO + ((size_t)(b * NSEQ) + n0 + c) * DM + kk * 32 + quad * 8);

    f32x4 acc = {0.f, 0.f, 0.f, 0.f};
#pragma unroll
    for (int kk = 0; kk < 4; ++kk)
        acc = mfma16(*reinterpret_cast<const u16x8*>(
                         WfcB + (t * 16 + c) * DM + kk * 32 + quad * 8),
                     af[kk], acc);
#pragma unroll
    for (int r = 0; r < 4; ++r)
        out[(size_t)(b * DM + t * 16 + quad * 4 + r) * NSEQ + n0 + c] =
            acc[r] + bfc[t * 16 + quad * 4 + r];
}

// ---------------------------------------------------------------------------
extern "C" void kernel_launch(void* const* d_in, const int* in_sizes, int n_in,
                              void* d_out, int out_size, void* d_ws, size_t ws_size,
                              hipStream_t stream)
{
    const float* x    = (const float*)d_in[0];
    const float* mask = (const float*)d_in[1];
    const float* Wq   = (const float*)d_in[2];
    const float* bq   = (const float*)d_in[3];
    const float* Wk   = (const float*)d_in[4];
    const float* bk   = (const float*)d_in[5];
    const float* Wv   = (const float*)d_in[6];
    const float* bv   = (const float*)d_in[7];
    const float* Wfc  = (const float*)d_in[8];
    const float* bfc  = (const float*)d_in[9];
    float* out = (float*)d_out;

    const size_t QKV_ELEMS = (size_t)BSZ * NH * NSEQ * DK;  // 1,048,576
    unsigned short* Q    = (unsigned short*)d_ws;
    unsigned short* Kb   = Q + QKV_ELEMS;
    unsigned short* AO   = Kb + QKV_ELEMS;
    unsigned short* WfcB = AO + QKV_ELEMS;
    unsigned short* VW2  = WfcB + DM * DM;   // [bh][g=128][lane=64][8] bf16
    unsigned short* WqB  = VW2 + (size_t)BSZ * NH * 128 * 512;
    unsigned short* WkB  = WqB + DM * DM;
    unsigned short* WvB  = WkB + DM * DM;

    k_prep<<<96, 256, 0, stream>>>(Wq, Wk, Wv, Wfc, mask,
                                   WqB, WkB, WvB, WfcB, VW2);
    k_qkv<<<256, 768, 0, stream>>>(x, WqB, bq, WkB, bk, WvB, bv, mask,
                                   Q, Kb, VW2);
    k_attn<<<1024, 256, 0, stream>>>(Q, Kb, VW2, AO);
    k_fc<<<1024, 256, 0, stream>>>(AO, WfcB, bfc, out);
}

// Round 9
// 115.963 us; speedup vs baseline: 1.1215x; 1.0198x over previous
//
#include <hip/hip_runtime.h>
#include <stdint.h>

#define BSZ  4
#define NSEQ 2048
#define DM   128
#define NH   8
#define DK   16
#define LOG2E 1.4426950408889634f
// LOG2E / sqrt(128): folded into Wq/bq so scores exit QK^T in log2 domain
#define SCALE_QL 0.1275156338341935f
// mask weight: w = mask * 2^-18 (exact in bf16); folded into V' and the
// l-row of the PV A-tile. p = exp2(S) stays <= ~2^10, l ~ 1e-2 -> safe fp32.
#define W_SCALE 3.814697265625e-6f

typedef __bf16          bf16x8v __attribute__((ext_vector_type(8)));
typedef float           f32x4   __attribute__((ext_vector_type(4)));
typedef float           f32x16  __attribute__((ext_vector_type(16)));
typedef unsigned short  u16x8   __attribute__((ext_vector_type(8)));
typedef unsigned short  u16x4   __attribute__((ext_vector_type(4)));
typedef unsigned int    u32x2   __attribute__((ext_vector_type(2)));
typedef unsigned int    u32x4   __attribute__((ext_vector_type(4)));

__device__ __forceinline__ unsigned short f2bf(float f) {
    unsigned u = __float_as_uint(f);
    u = (u + 0x7fffu + ((u >> 16) & 1u)) >> 16;
    return (unsigned short)u;
}

__device__ __forceinline__ unsigned int pack2bf(float a, float b) {
#if __has_builtin(__builtin_amdgcn_cvt_pk_bf16_f32)
    typedef __bf16 bf16x2 __attribute__((ext_vector_type(2)));
    bf16x2 v = __builtin_amdgcn_cvt_pk_bf16_f32(a, b);
    return __builtin_bit_cast(unsigned int, v);
#else
    return (unsigned)f2bf(a) | ((unsigned)f2bf(b) << 16);
#endif
}

__device__ __forceinline__ float exp2_(float x) {
#if __has_builtin(__builtin_amdgcn_exp2f)
    return __builtin_amdgcn_exp2f(x);
#else
    return exp2f(x);
#endif
}

__device__ __forceinline__ f32x4 mfma16(u16x8 a, u16x8 b, f32x4 c) {
    return __builtin_amdgcn_mfma_f32_16x16x32_bf16(
        __builtin_bit_cast(bf16x8v, a), __builtin_bit_cast(bf16x8v, b), c, 0, 0, 0);
}
__device__ __forceinline__ f32x16 mfma32(u16x8 a, u16x8 b, f32x16 c) {
    return __builtin_amdgcn_mfma_f32_32x32x16_bf16(
        __builtin_bit_cast(bf16x8v, a), __builtin_bit_cast(bf16x8v, b), c, 0, 0, 0);
}

// ROUND-9: shuffle-free P->B-frag. Packing S regs 0..7 (and 8..15) straight
// into a B-frag makes the k-slot->kv map a FIXED involution
//   rho = [0,1,2,3, 8,9,10,11, 4,5,6,7, 12,13,14,15]   (k 4-7 <-> 8-11)
// (from the validated S layout kv=(r&3)+8*(r>>2)+4*hi and the validated
// B-frag layout k=8*hi+j). rho is absorbed into the PV A-tile: k_qkv/k_prep
// write V'/w column o at k-slot rho(o): khalf=(o>>2)&1, j=(o&3)+4*((o>>3)&1).
// Result: zero DS ops and zero cndmasks in the attention main loop.
__device__ __forceinline__ void build_bfrags(const f32x16& S, u16x8& bfe, u16x8& bfo) {
    const u32x4 f1 = {pack2bf(S[0],  S[1]),  pack2bf(S[2],  S[3]),
                      pack2bf(S[4],  S[5]),  pack2bf(S[6],  S[7])};
    const u32x4 f2 = {pack2bf(S[8],  S[9]),  pack2bf(S[10], S[11]),
                      pack2bf(S[12], S[13]), pack2bf(S[14], S[15])};
    bfe = __builtin_bit_cast(u16x8, f1);
    bfo = __builtin_bit_cast(u16x8, f2);
}

// ---------------------------------------------------------------------------
// k_prep: one-shot weight conversion + mask weave. Converts Wq (pre-scaled
// to log2 domain), Wk, Wv, Wfc to bf16 once, and weaves w = bf16(mask*2^-18)
// into VW2 row 16 at rho-permuted k-slots. grid = 96 x 256.
// ---------------------------------------------------------------------------
__global__ __launch_bounds__(256) void k_prep(
    const float* __restrict__ Wq, const float* __restrict__ Wk,
    const float* __restrict__ Wv, const float* __restrict__ Wfc,
    const float* __restrict__ mask,
    unsigned short* __restrict__ WqB, unsigned short* __restrict__ WkB,
    unsigned short* __restrict__ WvB, unsigned short* __restrict__ WfcB,
    unsigned short* __restrict__ VW2)
{
    const int gt = blockIdx.x * 256 + threadIdx.x;
    if (gt < DM * DM) {
        WqB[gt]  = f2bf(Wq[gt] * SCALE_QL);
        WkB[gt]  = f2bf(Wk[gt]);
        WvB[gt]  = f2bf(Wv[gt]);
        WfcB[gt] = f2bf(Wfc[gt]);
    } else if (gt < DM * DM + BSZ * NSEQ) {
        const int i  = gt - DM * DM;          // i = b*NSEQ + kv
        const int kv = i & (NSEQ - 1);
        const int bb = i >> 11;
        const unsigned short w16 = f2bf(mask[i] * W_SCALE);
        // rho-permuted k-slot: khalf=(kv>>2)&1, j=(kv&3)+4*((kv>>3)&1)
        unsigned short* dst = VW2 +
            (((size_t)(bb * NH) * 128 + (kv >> 4)) << 9) +
            (16 + ((kv >> 2) & 1) * 32) * 8 + (kv & 3) + 4 * ((kv >> 3) & 1);
#pragma unroll
        for (int hh = 0; hh < NH; ++hh)
            dst[(size_t)hh * 128 * 512] = w16;
    }
}

// ---------------------------------------------------------------------------
// k_qkv: C^T-form projection, x-tile staged in LDS (coalesced f32x4 loads).
// grid = b(4) x n-tile32(64), 768 threads = 12 waves = mat(3) x nsub(2) x th(2).
// W pre-converted bf16 (k_prep). Q,K -> [B][H][N][16] bf16.
// V is emitted directly as the PV A-tile VW2[bh][g=kv/16][lane][8] with the
// rho column permutation (see build_bfrags comment):
//   k-slot of column o: khalf=(o>>2)&1 (lane = row + 32*khalf),
//   j=(o&3)+4*((o>>3)&1). Rows 0-15 = V'[dk] (V scaled by w=mask*2^-18),
//   row 16 = w (written by k_prep), rows 17-31 = garbage (C rows unread).
// ---------------------------------------------------------------------------
__global__ __launch_bounds__(768) void k_qkv(
    const float* __restrict__ x,
    const unsigned short* __restrict__ WqB, const float* __restrict__ bq,
    const unsigned short* __restrict__ WkB, const float* __restrict__ bk,
    const unsigned short* __restrict__ WvB, const float* __restrict__ bv,
    const float* __restrict__ mask,
    unsigned short* __restrict__ Q, unsigned short* __restrict__ Kb,
    unsigned short* __restrict__ VW2)
{
    __shared__ __align__(16) float xs[DM * 36];   // 32 n + 4 pad
    const int tid = threadIdx.x;

    const int b  = blockIdx.x >> 6;
    const int n0 = (blockIdx.x & 63) << 5;

    // stage x[b][0..128][n0..n0+32] -> xs[d*36 + j], fully coalesced
#pragma unroll
    for (int i = tid; i < 1024; i += 768) {
        const int d = i >> 3, c4 = (i & 7) << 2;
        *reinterpret_cast<f32x4*>(&xs[d * 36 + c4]) =
            *reinterpret_cast<const f32x4*>(x + (size_t)(b * DM + d) * NSEQ + n0 + c4);
    }
    __syncthreads();

    const int lane = tid & 63;
    const int wv   = tid >> 6;          // 0..11
    const int mat  = wv >> 2;           // 0..2
    const int nt   = (wv >> 1) & 1;     // n subtile
    const int th   = wv & 1;            // t half
    const int c    = lane & 15;
    const int quad = lane >> 4;
    const int col  = n0 + nt * 16 + c;

    // B-frag from LDS: B[k=d][n=c]
    u16x8 xf[4];
#pragma unroll
    for (int kk = 0; kk < 4; ++kk) {
        float f[8];
#pragma unroll
        for (int j = 0; j < 8; ++j)
            f[j] = xs[(kk * 32 + quad * 8 + j) * 36 + nt * 16 + c];
        u32x4 u = {pack2bf(f[0], f[1]), pack2bf(f[2], f[3]),
                   pack2bf(f[4], f[5]), pack2bf(f[6], f[7])};
        xf[kk] = __builtin_bit_cast(u16x8, u);
    }

    const unsigned short* W = (mat == 0) ? WqB : (mat == 1) ? WkB : WvB;
    const float* bias = (mat == 0) ? bq : (mat == 1) ? bk : bv;
    const float  sc   = (mat == 0) ? SCALE_QL : 1.0f;   // bias scale only
    // V' scale: w = mask * 2^-18 for this column
    const float  vwsc = (mat == 2) ? mask[b * NSEQ + col] * W_SCALE : 0.f;
    const int    g    = col >> 4;
    // rho-permuted k-slot for kv-column col (round-9 change)
    const int    roff = ((col >> 2) & 1) * 32;
    const int    j7   = (col & 3) | (((col >> 3) & 1) << 2);

#pragma unroll
    for (int tt = 0; tt < 4; ++tt) {
        const int t = th * 4 + tt;
        f32x4 acc = {0.f, 0.f, 0.f, 0.f};
#pragma unroll
        for (int kk = 0; kk < 4; ++kk)
            acc = mfma16(*reinterpret_cast<const u16x8*>(
                             W + (t * 16 + c) * DM + kk * 32 + quad * 8),
                         xf[kk], acc);
        if (mat == 2) {
            unsigned short* vwp = VW2 +
                (((size_t)((b * NH + t) * 128 + g)) << 9) + j7;
#pragma unroll
            for (int r = 0; r < 4; ++r)
                vwp[(quad * 4 + r + roff) * 8] =
                    f2bf((acc[r] + bias[t * 16 + quad * 4 + r]) * vwsc);
        } else {
            u16x4 pk;
#pragma unroll
            for (int r = 0; r < 4; ++r)
                pk[r] = f2bf(acc[r] + bias[t * 16 + quad * 4 + r] * sc);
            *reinterpret_cast<u16x4*>(
                (mat == 0 ? Q : Kb) + ((size_t)(b * NH + t) * NSEQ + col) * DK +
                quad * 4) = pk;
        }
    }
}

// ---------------------------------------------------------------------------
// k_attn: fixed-scale flash attention, fully register-resident main loop.
// ROUND-9 CHANGE: the P->PV shuffle is gone. S regs pack STRAIGHT into
// B-frags (8 cvt_pk per tile, no ds_bpermute, no cndmask); the k-slot->kv
// involution rho this induces is pre-absorbed into the VW2 A-tile by
// k_qkv/k_prep. Main loop now has ZERO DS ops; exp2->PV dependency chain
// loses the ~130cy LDS-shuffle exposure (x2 per iteration).
// Two query-tiles per block (round 8): grid 1024 = 4 blocks/CU, shared
// nk/va across streams. l falls out of PV C-row 16 (w row in A-tile).
// LDS (21.5 KB) only for the epilogue merge.
// __launch_bounds__(256,4): proven no-spill regime; tripwire WRITE_SIZE.
// ---------------------------------------------------------------------------
__global__ __launch_bounds__(256, 4) void k_attn(
    const unsigned short* __restrict__ Q,
    const unsigned short* __restrict__ Kb,
    const unsigned short* __restrict__ VW2,
    unsigned short* __restrict__ AO)
{
    __shared__ __align__(16) float smem[256 + 2 * 4 * 32 * 20];  // Lsm + Osm
    const int tid  = threadIdx.x;
    const int lane = tid & 63;
    const int w    = tid >> 6;      // kv quarter
    const int q32  = lane & 31;
    const int hi   = lane >> 5;

    // XCD-chunked swizzle: 1024 blocks -> 128-block chunk per XCD
    // (= 4 complete (b,h) groups of 32 blocks each).
    const int bid = ((int)blockIdx.x & 7) * 128 + ((int)blockIdx.x >> 3);
    const int b  = bid >> 8;
    const int h  = (bid >> 5) & 7;
    const int n0 = (bid & 31) << 6;     // 64-query tile
    const int bh = b * NH + h;

    // Q B-frags for the two 32-query sub-tiles (prescaled to log2 domain)
    const u16x8 uqA = *reinterpret_cast<const u16x8*>(
        Q + ((size_t)bh * NSEQ + n0 + q32) * DK + 8 * hi);
    const u16x8 uqB = *reinterpret_cast<const u16x8*>(
        Q + ((size_t)bh * NSEQ + n0 + 32 + q32) * DK + 8 * hi);

    const unsigned short* Kp = Kb + (size_t)bh * NSEQ * DK + 8 * hi;
    // PV A-tile: lane-linear, 16 B/lane fully coalesced
    const unsigned short* Ap = VW2 + (((size_t)bh * 128) << 9) + lane * 8;

    f32x16 accA = {};                 // O^T rows 0-15, l at row 16 (tile A)
    f32x16 accB = {};                 // (tile B)
    const f32x16 z16 = {};
    const int kvb = w * (NSEQ / 4);

    // prefetch iteration 0's K fragments
    u16x8 nk0 = *reinterpret_cast<const u16x8*>(Kp + (size_t)(kvb + q32) * DK);
    u16x8 nk1 = *reinterpret_cast<const u16x8*>(Kp + (size_t)(kvb + 32 + q32) * DK);

#pragma unroll 1
    for (int it = 0; it < 8; ++it) {
        const int kv0 = kvb + it * 64;
        const int g0  = kv0 >> 4;
        // PV A-frags for this iter's 4 K=16 tiles (L2-resident, shared A/B)
        const u16x8 va0 = *reinterpret_cast<const u16x8*>(Ap + ((size_t)(g0    ) << 9));
        const u16x8 va1 = *reinterpret_cast<const u16x8*>(Ap + ((size_t)(g0 + 1) << 9));
        const u16x8 va2 = *reinterpret_cast<const u16x8*>(Ap + ((size_t)(g0 + 2) << 9));
        const u16x8 va3 = *reinterpret_cast<const u16x8*>(Ap + ((size_t)(g0 + 3) << 9));

        // --- kv [kv0, kv0+32): two independent S-streams off nk0 ---
        {
            __builtin_amdgcn_s_setprio(1);
            f32x16 SA = mfma32(nk0, uqA, z16);   // S^T[kv][q] (log2 domain)
            f32x16 SB = mfma32(nk0, uqB, z16);
            __builtin_amdgcn_s_setprio(0);
            if (it < 7)
                nk0 = *reinterpret_cast<const u16x8*>(
                    Kp + (size_t)(kv0 + 64 + q32) * DK);
#pragma unroll
            for (int i = 0; i < 16; ++i) SA[i] = exp2_(SA[i]);
#pragma unroll
            for (int i = 0; i < 16; ++i) SB[i] = exp2_(SB[i]);
            u16x8 bfA1, bfA2, bfB1, bfB2;
            build_bfrags(SA, bfA1, bfA2);
            build_bfrags(SB, bfB1, bfB2);
            __builtin_amdgcn_s_setprio(1);
            accA = mfma32(va0, bfA1, accA);
            accB = mfma32(va0, bfB1, accB);
            accA = mfma32(va1, bfA2, accA);
            accB = mfma32(va1, bfB2, accB);
            __builtin_amdgcn_s_setprio(0);
        }

        // --- kv [kv0+32, kv0+64): same off nk1 ---
        {
            __builtin_amdgcn_s_setprio(1);
            f32x16 SA = mfma32(nk1, uqA, z16);
            f32x16 SB = mfma32(nk1, uqB, z16);
            __builtin_amdgcn_s_setprio(0);
            if (it < 7)
                nk1 = *reinterpret_cast<const u16x8*>(
                    Kp + (size_t)(kv0 + 96 + q32) * DK);
#pragma unroll
            for (int i = 0; i < 16; ++i) SA[i] = exp2_(SA[i]);
#pragma unroll
            for (int i = 0; i < 16; ++i) SB[i] = exp2_(SB[i]);
            u16x8 bfA1, bfA2, bfB1, bfB2;
            build_bfrags(SA, bfA1, bfA2);
            build_bfrags(SB, bfB1, bfB2);
            __builtin_amdgcn_s_setprio(1);
            accA = mfma32(va2, bfA1, accA);
            accB = mfma32(va2, bfB1, accB);
            accA = mfma32(va3, bfA2, accA);
            accB = mfma32(va3, bfB2, accB);
            __builtin_amdgcn_s_setprio(0);
        }
    }

    // ---- 4-wave merge, two tiles ----
    // acc layout: col q=q32; hi=0 regs: dk 0-3 (r0-3), dk 8-11 (r4-7), l (r8)
    //             hi=1 regs: dk 4-7 (r0-3), dk 12-15 (r4-7)
    float* Lsm = smem;            // [t2][w][32]
    float* Osm = smem + 256;      // [t2][w][q*20 + dk], tile stride 2560
    {
        float* Orow = Osm + w * 640 + q32 * 20;
        *reinterpret_cast<f32x4*>(Orow + (hi ? 4 : 0)) =
            f32x4{accA[0], accA[1], accA[2], accA[3]};
        *reinterpret_cast<f32x4*>(Orow + (hi ? 12 : 8)) =
            f32x4{accA[4], accA[5], accA[6], accA[7]};
        if (!hi) Lsm[w * 32 + q32] = accA[8];
        float* Orow2 = Orow + 2560;
        *reinterpret_cast<f32x4*>(Orow2 + (hi ? 4 : 0)) =
            f32x4{accB[0], accB[1], accB[2], accB[3]};
        *reinterpret_cast<f32x4*>(Orow2 + (hi ? 12 : 8)) =
            f32x4{accB[4], accB[5], accB[6], accB[7]};
        if (!hi) Lsm[128 + w * 32 + q32] = accB[8];
    }
    __syncthreads();

    const int q   = tid >> 3;              // 0..31
    const int dk2 = (tid & 7) * 2;         // 0,2,..,14
#pragma unroll
    for (int t2 = 0; t2 < 2; ++t2) {
        const float* Lt = Lsm + t2 * 128;
        const float l = Lt[q] + Lt[32 + q] + Lt[64 + q] + Lt[96 + q];
        const float* Oq = Osm + t2 * 2560 + q * 20 + dk2;
        const float v0 = Oq[0] + Oq[640] + Oq[1280] + Oq[1920];
        const float v1 = Oq[1] + Oq[641] + Oq[1281] + Oq[1921];
        const float inv = 1.0f / l;
        *reinterpret_cast<unsigned int*>(
            AO + ((size_t)(b * NSEQ) + n0 + t2 * 32 + q) * DM + h * DK + dk2) =
            pack2bf(v0 * inv, v1 * inv);
    }
}

// ---------------------------------------------------------------------------
// k_fc: C^T-form FC, output directly in (B, D, N).
// grid = b(4) x n-tile(128) x t-half(2), 4 waves, wave = one d'-tile.
// ---------------------------------------------------------------------------
__global__ __launch_bounds__(256) void k_fc(
    const unsigned short* __restrict__ AO,
    const unsigned short* __restrict__ WfcB, const float* __restrict__ bfc,
    float* __restrict__ out)
{
    const int lane = threadIdx.x & 63;
    const int w    = threadIdx.x >> 6;
    const int c    = lane & 15;
    const int quad = lane >> 4;
    const int b    = blockIdx.x >> 8;
    const int n0   = ((blockIdx.x >> 1) & 127) << 4;
    const int t    = (blockIdx.x & 1) * 4 + w;

    u16x8 af[4];
#pragma unroll
    for (int kk = 0; kk < 4; ++kk)
        af[kk] = *reinterpret_cast<const u16x8*>(
            AO + ((size_t)(b * NSEQ) + n0 + c) * DM + kk * 32 + quad * 8);

    f32x4 acc = {0.f, 0.f, 0.f, 0.f};
#pragma unroll
    for (int kk = 0; kk < 4; ++kk)
        acc = mfma16(*reinterpret_cast<const u16x8*>(
                         WfcB + (t * 16 + c) * DM + kk * 32 + quad * 8),
                     af[kk], acc);
#pragma unroll
    for (int r = 0; r < 4; ++r)
        out[(size_t)(b * DM + t * 16 + quad * 4 + r) * NSEQ + n0 + c] =
            acc[r] + bfc[t * 16 + quad * 4 + r];
}

// ---------------------------------------------------------------------------
extern "C" void kernel_launch(void* const* d_in, const int* in_sizes, int n_in,
                              void* d_out, int out_size, void* d_ws, size_t ws_size,
                              hipStream_t stream)
{
    const float* x    = (const float*)d_in[0];
    const float* mask = (const float*)d_in[1];
    const float* Wq   = (const float*)d_in[2];
    const float* bq   = (const float*)d_in[3];
    const float* Wk   = (const float*)d_in[4];
    const float* bk   = (const float*)d_in[5];
    const float* Wv   = (const float*)d_in[6];
    const float* bv   = (const float*)d_in[7];
    const float* Wfc  = (const float*)d_in[8];
    const float* bfc  = (const float*)d_in[9];
    float* out = (float*)d_out;

    const size_t QKV_ELEMS = (size_t)BSZ * NH * NSEQ * DK;  // 1,048,576
    unsigned short* Q    = (unsigned short*)d_ws;
    unsigned short* Kb   = Q + QKV_ELEMS;
    unsigned short* AO   = Kb + QKV_ELEMS;
    unsigned short* WfcB = AO + QKV_ELEMS;
    unsigned short* VW2  = WfcB + DM * DM;   // [bh][g=128][lane=64][8] bf16
    unsigned short* WqB  = VW2 + (size_t)BSZ * NH * 128 * 512;
    unsigned short* WkB  = WqB + DM * DM;
    unsigned short* WvB  = WkB + DM * DM;

    k_prep<<<96, 256, 0, stream>>>(Wq, Wk, Wv, Wfc, mask,
                                   WqB, WkB, WvB, WfcB, VW2);
    k_qkv<<<256, 768, 0, stream>>>(x, WqB, bq, WkB, bk, WvB, bv, mask,
                                   Q, Kb, VW2);
    k_attn<<<1024, 256, 0, stream>>>(Q, Kb, VW2, AO);
    k_fc<<<1024, 256, 0, stream>>>(AO, WfcB, bfc, out);
}